// Round 7
// baseline (702.677 us; speedup 1.0000x reference)
//
#include <hip/hip_runtime.h>
#include <hip/hip_bf16.h>

// DecoderInputEmbedding — B=4, T=1024, F=6144 (SW=96 x FB=64), EMB=512, H=3, dh=32.
// All inputs fp32 (o_enc int32), output fp32. Internals bf16 (2%-rel threshold).
// R7: weight B-fragments loaded DIRECT from global (pre-transposed, L2-resident)
// -> attn_ffn has only 3 barriers; gemm: B direct from blocked WeT, A
// double-buffered with register prefetch, split-K=2, atomicAdd into bias-
// initialized Y.
//
// ws layout (bytes):
//   M    @ 0          bf16 4096x6144
//   Y    @ 50331648   fp32 4096x512   (bias-initialized, gemm atomicAdds)
//   sums @ 58720256   2 floats
//   bids @ 58720320   4x1024 int
//   Wc   @ 58736768   canonical bf16 weights

typedef __attribute__((ext_vector_type(8))) short bf16x8;   // 8 bf16 = 4 VGPR
typedef __attribute__((ext_vector_type(4))) float f32x4;    // MFMA C/D

struct PtrTab { const void* p[16]; };

// Wc element offsets (multiples of 8 -> 16B-aligned rows)
enum : int {
  O_WQT = 0,        // [96][104]  W^T padded
  O_BQ  = 9984,
  O_WKT = 10080,
  O_BK  = 20064,
  O_WVT = 20160,
  O_BV  = 30144,
  O_ER  = 30240,    // [64][32]
  O_W1T = 32288,    // [384][104]
  O_B1  = 72224,
  O_W2C = 72608,    // [12][96][40]  W2^T k-chunks of 32, padded to 40
  O_B2  = 118688,
  O_WET = 118784,   // [8 nt][96 kt][64 n'][64 k']
  O_BE  = 3264512
};

__device__ __forceinline__ float b2f(__hip_bfloat16 v) { return __bfloat162float(v); }
__device__ __forceinline__ __hip_bfloat16 f2b(float v) { return __float2bfloat16(v); }

__global__ void convert_kernel(PtrTab tab, __hip_bfloat16* __restrict__ Wc) {
    const int g = blockIdx.x * 256 + threadIdx.x;
    const int stride = gridDim.x * 256;
    const float* Wq = (const float*)tab.p[3];
    const float* bq = (const float*)tab.p[4];
    const float* Wk = (const float*)tab.p[5];
    const float* bk = (const float*)tab.p[6];
    const float* Wv = (const float*)tab.p[7];
    const float* bv = (const float*)tab.p[8];
    const float* Er = (const float*)tab.p[9];
    const float* W1 = (const float*)tab.p[10];
    const float* b1 = (const float*)tab.p[11];
    const float* W2 = (const float*)tab.p[12];
    const float* b2 = (const float*)tab.p[13];

    for (int t = 0; t < 3; ++t) {
        const float* W = (t == 0 ? Wq : t == 1 ? Wk : Wv);
        __hip_bfloat16* d = Wc + (t == 0 ? O_WQT : t == 1 ? O_WKT : O_WVT);
        for (int i = g; i < 9984; i += stride) {
            int j = i / 104, c = i - j * 104;
            d[i] = (c < 96) ? f2b(W[c * 96 + j]) : f2b(0.0f);
        }
    }
    for (int i = g; i < 96; i += stride) {
        Wc[O_BQ + i] = f2b(bq[i]);
        Wc[O_BK + i] = f2b(bk[i]);
        Wc[O_BV + i] = f2b(bv[i]);
        Wc[O_B2 + i] = f2b(b2[i]);
    }
    for (int i = g; i < 2048; i += stride) Wc[O_ER + i] = f2b(Er[i]);
    for (int i = g; i < 39936; i += stride) {
        int j = i / 104, c = i - j * 104;
        Wc[O_W1T + i] = (c < 96) ? f2b(W1[c * 384 + j]) : f2b(0.0f);
    }
    for (int i = g; i < 384; i += stride) Wc[O_B1 + i] = f2b(b1[i]);
    for (int i = g; i < 46080; i += stride) {
        int kc = i / 3840, r = i - kc * 3840;
        int n = r / 40, kk = r - n * 40;
        Wc[O_W2C + i] = (kk < 32) ? f2b(W2[(kc * 32 + kk) * 96 + n]) : f2b(0.0f);
    }
}

// We (6144x512 fp32) -> blocked WeT: [nt][kt][n'][k'] = We[kt*64+k'][nt*64+n']
__global__ __launch_bounds__(256) void transpose_we_kernel(
    const float* __restrict__ We, __hip_bfloat16* __restrict__ Wc)
{
    __shared__ __hip_bfloat16 tile[64][65];
    const int kt = blockIdx.x, nt = blockIdx.y, tid = threadIdx.x;
    const int k0 = kt * 64, n0 = nt * 64;
    for (int e = tid; e < 4096; e += 256) {
        int kk = e >> 6, nn = e & 63;
        tile[nn][kk] = f2b(We[(size_t)(k0 + kk) * 512 + n0 + nn]);
    }
    __syncthreads();
    __hip_bfloat16* dst = Wc + O_WET + ((size_t)nt * 96 + kt) * 4096;
    for (int e = tid; e < 4096; e += 256)
        dst[e] = tile[e >> 6][e & 63];
}

// Y[i] = be[i & 511]  (bias pre-init; gemm atomicAdds partial sums)
__global__ __launch_bounds__(256) void ybias_kernel(const float* __restrict__ be,
                                                    float* __restrict__ Y) {
    const int i = blockIdx.x * 256 + threadIdx.x;       // float4 index, 524288 total
    ((float4*)Y)[i] = ((const float4*)be)[i & 127];
}

// Fragment layouts (HW-verified): A: m=lane&15, k=quad*8+j; B from B^T same;
// C/D: col=lane&15, row=quad*4+reg.
__global__ __launch_bounds__(256) void attn_ffn_kernel(
    const float* __restrict__ x, const __hip_bfloat16* __restrict__ Wc,
    __hip_bfloat16* __restrict__ M)
{
    const int n = blockIdx.x, tid = threadIdx.x;
    const int w = tid >> 6, lane = tid & 63, quad = lane >> 4, ln = lane & 15;

    __shared__ __align__(16) char smem[49664];
    __hip_bfloat16* xs  = (__hip_bfloat16*)(smem);          // [64][104] x / att
    __hip_bfloat16* PB  = (__hip_bfloat16*)(smem + 13312);  // [64][72] qer / P
    __hip_bfloat16* kS  = (__hip_bfloat16*)(smem + 22528);  // [64][104] Qscr / K
    __hip_bfloat16* vT  = (__hip_bfloat16*)(smem + 35840);  // [96][72] V^T
    __hip_bfloat16* hid = (__hip_bfloat16*)(smem + 22528);  // [64][200] FFN hidden

    // stage x transposed: xs[l=f][d=s] = x[n*6144 + s*64 + f] (float4 reads)
    const float4* xb4 = (const float4*)(x + (size_t)n * 6144);
    for (int e4 = tid; e4 < 1536; e4 += 256) {
        float4 v = xb4[e4];
        int e = e4 * 4, d = e >> 6, l = e & 63;
        xs[(l + 0) * 104 + d] = f2b(v.x);
        xs[(l + 1) * 104 + d] = f2b(v.y);
        xs[(l + 2) * 104 + d] = f2b(v.z);
        xs[(l + 3) * 104 + d] = f2b(v.w);
    }
    __syncthreads();                                        // barrier 1

    const int rowb = 16 * w + quad * 4;
    const f32x4 z4 = {0.f, 0.f, 0.f, 0.f};
    bf16x8 aqr[3];                                          // Q A-frags (regs)

    // ---------- phase A: Q/K/V = xs(64x96) @ W + b (B-frags direct global) ----------
    for (int t = 0; t < 3; ++t) {
        const __hip_bfloat16* WT = Wc + (t == 0 ? O_WQT : t == 1 ? O_WKT : O_WVT);
        const __hip_bfloat16* bt = Wc + (t == 0 ? O_BQ : t == 1 ? O_BK : O_BV);
        for (int half = 0; half < 2; ++half) {
            const int j0 = half * 48;
            f32x4 acc[3] = {z4, z4, z4};
            #pragma unroll
            for (int ks = 0; ks < 3; ++ks) {
                bf16x8 a = *(const bf16x8*)(xs + (16 * w + ln) * 104 + ks * 32 + quad * 8);
                #pragma unroll
                for (int ct = 0; ct < 3; ++ct) {
                    bf16x8 b = *(const bf16x8*)(WT + (j0 + ct * 16 + ln) * 104 + ks * 32 + quad * 8);
                    acc[ct] = __builtin_amdgcn_mfma_f32_16x16x32_bf16(a, b, acc[ct], 0, 0, 0);
                }
            }
            #pragma unroll
            for (int ct = 0; ct < 3; ++ct) {
                int col = j0 + ct * 16 + ln;
                float bb = b2f(bt[col]);
                if (t < 2) {                                // Q scratch / K (wave-local rows)
                    #pragma unroll
                    for (int r = 0; r < 4; ++r)
                        kS[(rowb + r) * 104 + col] = f2b(acc[ct][r] + bb);
                } else {
                    #pragma unroll
                    for (int r = 0; r < 4; ++r)
                        vT[col * 72 + (rowb + r)] = f2b(acc[ct][r] + bb);
                }
            }
            if (t == 0 && half == 1) {                      // own-wave rows -> no barrier
                #pragma unroll
                for (int h = 0; h < 3; ++h)
                    aqr[h] = *(const bf16x8*)(kS + (16 * w + ln) * 104 + h * 32 + quad * 8);
            }
        }
    }

    bf16x8 erf[4];                                          // Er B-frags (global, cached)
    #pragma unroll
    for (int tn = 0; tn < 4; ++tn)
        erf[tn] = *(const bf16x8*)(Wc + O_ER + (16 * tn + ln) * 32 + quad * 8);
    __syncthreads();                                        // barrier 2: K/V visible

    // ---------- phase B: MFMA attention (barrier-free) ----------
    for (int h = 0; h < 3; ++h) {
        const int c0 = h * 32;
        bf16x8 aq = aqr[h];
        #pragma unroll
        for (int tn = 0; tn < 4; ++tn) {                    // Qer -> PB (own rows)
            f32x4 q4 = __builtin_amdgcn_mfma_f32_16x16x32_bf16(aq, erf[tn], z4, 0, 0, 0);
            #pragma unroll
            for (int r = 0; r < 4; ++r)
                PB[(rowb + r) * 72 + 16 * tn + ln] = f2b(q4[r]);
        }
        float sco[4][4];
        #pragma unroll
        for (int tn = 0; tn < 4; ++tn) {
            bf16x8 kf = *(const bf16x8*)(kS + (16 * tn + ln) * 104 + c0 + quad * 8);
            f32x4 s1 = __builtin_amdgcn_mfma_f32_16x16x32_bf16(aq, kf, z4, 0, 0, 0);
            #pragma unroll
            for (int r = 0; r < 4; ++r) sco[tn][r] = s1[r];
        }
        #pragma unroll
        for (int tn = 0; tn < 4; ++tn)
            #pragma unroll
            for (int r = 0; r < 4; ++r) {
                int row = rowb + r, col = 16 * tn + ln;
                if (col <= row)
                    sco[tn][r] = (sco[tn][r] + b2f(PB[row * 72 + col + 63 - row]))
                                 * 0.17677669529663687f;
                else
                    sco[tn][r] = -3.0e38f;
            }
        float mx[4], sm[4];
        #pragma unroll
        for (int r = 0; r < 4; ++r) {
            float m0 = fmaxf(fmaxf(sco[0][r], sco[1][r]), fmaxf(sco[2][r], sco[3][r]));
            #pragma unroll
            for (int d = 1; d < 16; d <<= 1) m0 = fmaxf(m0, __shfl_xor(m0, d, 64));
            mx[r] = m0;
        }
        #pragma unroll
        for (int tn = 0; tn < 4; ++tn)
            #pragma unroll
            for (int r = 0; r < 4; ++r) sco[tn][r] = __expf(sco[tn][r] - mx[r]);
        #pragma unroll
        for (int r = 0; r < 4; ++r) {
            float s0 = sco[0][r] + sco[1][r] + sco[2][r] + sco[3][r];
            #pragma unroll
            for (int d = 1; d < 16; d <<= 1) s0 += __shfl_xor(s0, d, 64);
            sm[r] = 1.0f / s0;
        }
        #pragma unroll
        for (int tn = 0; tn < 4; ++tn)
            #pragma unroll
            for (int r = 0; r < 4; ++r)
                PB[(rowb + r) * 72 + 16 * tn + ln] = f2b(sco[tn][r] * sm[r]);
        f32x4 oacc[2] = {z4, z4};
        #pragma unroll
        for (int ks2 = 0; ks2 < 2; ++ks2) {
            bf16x8 pa = *(const bf16x8*)(PB + (16 * w + ln) * 72 + ks2 * 32 + quad * 8);
            #pragma unroll
            for (int t2 = 0; t2 < 2; ++t2) {
                bf16x8 vb = *(const bf16x8*)(vT + (c0 + 16 * t2 + ln) * 72 + ks2 * 32 + quad * 8);
                oacc[t2] = __builtin_amdgcn_mfma_f32_16x16x32_bf16(pa, vb, oacc[t2], 0, 0, 0);
            }
        }
        #pragma unroll
        for (int t2 = 0; t2 < 2; ++t2)
            #pragma unroll
            for (int r = 0; r < 4; ++r)
                xs[(rowb + r) * 104 + c0 + 16 * t2 + ln] = f2b(oacc[t2][r]);
    }
    __syncthreads();                                        // barrier 3: hid overlays kS/vT

    // ---------- phase C: FFN (barrier-free; B-frags direct global) ----------
    f32x4 acc2[6] = {z4, z4, z4, z4, z4, z4};
    for (int jh = 0; jh < 2; ++jh) {
        for (int cc = 0; cc < 4; ++cc) {
            const int j0g = jh * 192 + cc * 48;
            f32x4 a1[3] = {z4, z4, z4};
            #pragma unroll
            for (int ks = 0; ks < 3; ++ks) {
                bf16x8 a = *(const bf16x8*)(xs + (16 * w + ln) * 104 + ks * 32 + quad * 8);
                #pragma unroll
                for (int ct = 0; ct < 3; ++ct) {
                    bf16x8 b = *(const bf16x8*)(Wc + O_W1T + (j0g + ct * 16 + ln) * 104 + ks * 32 + quad * 8);
                    a1[ct] = __builtin_amdgcn_mfma_f32_16x16x32_bf16(a, b, a1[ct], 0, 0, 0);
                }
            }
            #pragma unroll
            for (int ct = 0; ct < 3; ++ct) {
                int colg = j0g + ct * 16 + ln;
                int coll = cc * 48 + ct * 16 + ln;
                float bb = b2f(Wc[O_B1 + colg]);
                #pragma unroll
                for (int r = 0; r < 4; ++r)
                    hid[(rowb + r) * 200 + coll] = f2b(fmaxf(a1[ct][r] + bb, 0.f));
            }
        }
        for (int kc = 0; kc < 6; ++kc) {                    // hid read: own-wave rows
            const int kcg = jh * 6 + kc;
            bf16x8 a = *(const bf16x8*)(hid + (16 * w + ln) * 200 + kc * 32 + quad * 8);
            #pragma unroll
            for (int ct = 0; ct < 6; ++ct) {
                bf16x8 b = *(const bf16x8*)(Wc + O_W2C + kcg * 3840 + (ct * 16 + ln) * 40 + quad * 8);
                acc2[ct] = __builtin_amdgcn_mfma_f32_16x16x32_bf16(a, b, acc2[ct], 0, 0, 0);
            }
        }
    }

    // epilogue: M[n][d*64 + l] = acc2 + b2[d], packed 8B stores
    __hip_bfloat16* Mg = M + (size_t)n * 6144;
    #pragma unroll
    for (int ct = 0; ct < 6; ++ct) {
        int d = ct * 16 + ln;
        float bb = b2f(Wc[O_B2 + d]);
        union { __hip_bfloat16 h4[4]; uint2 u; } pk;
        #pragma unroll
        for (int r = 0; r < 4; ++r) pk.h4[r] = f2b(acc2[ct][r] + bb);
        *(uint2*)((char*)Mg + (size_t)(d * 64 + rowb) * 2) = pk.u;
    }
}

// Y += A(64 rows x Kslice) @ WeT(128 cols); split-K=2, A double-buffered w/
// register prefetch, B-frags direct from blocked WeT (L1/L2-resident).
__global__ __launch_bounds__(256) void gemm_kernel(
    const __hip_bfloat16* __restrict__ A,    // 4096 x 6144 (M workspace)
    const __hip_bfloat16* __restrict__ Wc,
    float* __restrict__ Y)                   // 4096 x 512 (bias-initialized)
{
    __shared__ __align__(16) __hip_bfloat16 As[2][64 * 72];
    const int row0 = blockIdx.x * 64, nt0 = blockIdx.y * 2, kh = blockIdx.z;
    const int tid = threadIdx.x;
    const int w = tid >> 6, lane = tid & 63, quad = lane >> 4, ln = lane & 15;
    const int e0 = tid, e1 = tid + 256;
    const int r0 = e0 >> 3, c0_ = (e0 & 7) * 8;
    const int r1 = e1 >> 3, c1_ = (e1 & 7) * 8;
    const size_t abase0 = (size_t)(row0 + r0) * 6144 + kh * 3072 + c0_;
    const size_t abase1 = (size_t)(row0 + r1) * 6144 + kh * 3072 + c1_;

    const f32x4 z4 = {0.f, 0.f, 0.f, 0.f};
    f32x4 acc[8] = {z4, z4, z4, z4, z4, z4, z4, z4};

    bf16x8 p0 = *(const bf16x8*)(A + abase0);
    bf16x8 p1 = *(const bf16x8*)(A + abase1);
    *(bf16x8*)(&As[0][r0 * 72 + c0_]) = p0;
    *(bf16x8*)(&As[0][r1 * 72 + c1_]) = p1;
    __syncthreads();

    for (int i = 0; i < 48; ++i) {
        const int cur = i & 1;
        if (i < 47) {
            p0 = *(const bf16x8*)(A + abase0 + (i + 1) * 64);
            p1 = *(const bf16x8*)(A + abase1 + (i + 1) * 64);
        }
        const int ktg = kh * 48 + i;
        #pragma unroll
        for (int ks = 0; ks < 2; ++ks) {
            bf16x8 a = *(const bf16x8*)(&As[cur][(16 * w + ln) * 72 + ks * 32 + quad * 8]);
            #pragma unroll
            for (int tnn = 0; tnn < 8; ++tnn) {
                const __hip_bfloat16* bp = Wc + O_WET
                    + ((size_t)(nt0 + (tnn >> 2)) * 96 + ktg) * 4096
                    + ((tnn & 3) * 16 + ln) * 64 + ks * 32 + quad * 8;
                acc[tnn] = __builtin_amdgcn_mfma_f32_16x16x32_bf16(a, *(const bf16x8*)bp, acc[tnn], 0, 0, 0);
            }
        }
        if (i < 47) {
            *(bf16x8*)(&As[cur ^ 1][r0 * 72 + c0_]) = p0;
            *(bf16x8*)(&As[cur ^ 1][r1 * 72 + c1_]) = p1;
        }
        __syncthreads();
    }
    #pragma unroll
    for (int tnn = 0; tnn < 8; ++tnn) {
        int col = (nt0 + (tnn >> 2)) * 64 + (tnn & 3) * 16 + ln;
        #pragma unroll
        for (int r = 0; r < 4; ++r)
            atomicAdd(&Y[(size_t)(row0 + 16 * w + quad * 4 + r) * 512 + col], acc[tnn][r]);
    }
}

__global__ void zero_kernel(float* __restrict__ sums) {
    if (threadIdx.x < 2) sums[threadIdx.x] = 0.f;
}

__global__ __launch_bounds__(256) void reduce_kernel(const float* __restrict__ Y,
                                                     float* __restrict__ sums) {
    float s = 0.f, s2 = 0.f;
    for (size_t i = (size_t)blockIdx.x * 256 + threadIdx.x; i < 2097152; i += (size_t)gridDim.x * 256) {
        float v = Y[i];
        s += v; s2 += v * v;
    }
    #pragma unroll
    for (int off = 1; off < 64; off <<= 1) {
        s  += __shfl_xor(s, off, 64);
        s2 += __shfl_xor(s2, off, 64);
    }
    __shared__ float r1[4], r2[4];
    const int lane = threadIdx.x & 63, wv = threadIdx.x >> 6;
    if (lane == 0) { r1[wv] = s; r2[wv] = s2; }
    __syncthreads();
    if (threadIdx.x == 0) {
        atomicAdd(&sums[0], r1[0] + r1[1] + r1[2] + r1[3]);
        atomicAdd(&sums[1], r2[0] + r2[1] + r2[2] + r2[3]);
    }
}

__global__ void segid_kernel(const int* __restrict__ o_enc, int* __restrict__ bids) {
    int b = threadIdx.x;
    if (b < 4) {
        const int* o = o_enc + b * 1024;
        int* bid = bids + b * 1024;
        int run = 0;
        int off = o[0];
        for (int t = 0; t < 1024; ++t) { run += o[t]; bid[t] = run - off; }
    }
}

__global__ __launch_bounds__(256) void final_kernel(
    const float* __restrict__ Y, const int* __restrict__ bids,
    const float* __restrict__ sums, const float* __restrict__ r_enc,
    float* __restrict__ out)
{
    const int bt = blockIdx.x;
    const int b = bt >> 10, t = bt & 1023;
    const float mu = sums[0] * (1.0f / 2097152.0f);
    const float var = sums[1] * (1.0f / 2097152.0f) - mu * mu;
    const float rstd = rsqrtf(var + 1e-8f);
    const int* bid = bids + b * 1024;
    const int my = bid[t];
    const bool is_start = (t == 0) || (bid[t - 1] != my);
    int t2 = t + 1;
    float invc = 0.f;
    if (is_start) {
        while (t2 < 1024 && bid[t2] == my) ++t2;
        invc = 1.0f / (float)(t2 - t);
    }
    for (int e = threadIdx.x; e < 512; e += 256) {
        const size_t base = (size_t)bt * 512 + e;
        float res = (Y[base] - mu) * rstd + r_enc[base];
        if (is_start) {
            float s = 0.f;
            for (int tt = t; tt < t2; ++tt)
                s += (Y[((size_t)(b * 1024 + tt)) * 512 + e] - mu) * rstd;
            res += s * invc;
        }
        out[base] = res;
    }
}

extern "C" void kernel_launch(void* const* d_in, const int* in_sizes, int n_in,
                              void* d_out, int out_size, void* d_ws, size_t ws_size,
                              hipStream_t stream) {
    PtrTab tab;
    for (int i = 0; i < 16; ++i) tab.p[i] = d_in[i];

    char* ws = (char*)d_ws;
    __hip_bfloat16* M  = (__hip_bfloat16*)ws;
    float* Y           = (float*)(ws + 50331648);
    float* sums        = (float*)(ws + 58720256);
    int*   bids        = (int*)(ws + 58720320);
    __hip_bfloat16* Wc = (__hip_bfloat16*)(ws + 58736768);

    convert_kernel<<<128, 256, 0, stream>>>(tab, Wc);
    transpose_we_kernel<<<dim3(96, 8), 256, 0, stream>>>((const float*)d_in[14], Wc);
    ybias_kernel<<<2048, 256, 0, stream>>>((const float*)d_in[15], Y);
    attn_ffn_kernel<<<4096, 256, 0, stream>>>((const float*)d_in[0], Wc, M);
    gemm_kernel<<<dim3(64, 4, 2), 256, 0, stream>>>(M, Wc, Y);
    zero_kernel<<<1, 64, 0, stream>>>(sums);
    reduce_kernel<<<512, 256, 0, stream>>>(Y, sums);
    segid_kernel<<<1, 64, 0, stream>>>((const int*)d_in[1], bids);
    final_kernel<<<4096, 256, 0, stream>>>(Y, bids, sums, (const float*)d_in[2], (float*)d_out);
}

// Round 8
// 524.670 us; speedup vs baseline: 1.3393x; 1.3393x over previous
//
#include <hip/hip_runtime.h>
#include <hip/hip_bf16.h>

// DecoderInputEmbedding — B=4, T=1024, F=6144 (SW=96 x FB=64), EMB=512, H=3, dh=32.
// All inputs fp32 (o_enc int32), output fp32. Internals bf16 (2%-rel threshold).
// R8: revert to R6 attn_ffn (LDS-staged weights; direct-global B-frags regressed
// in R7) with the wb/kS 768-B overlap FIXED; gemm rewritten: A+B double-buffered
// LDS with register prefetch, 1 barrier/iter, no split-K/atomics, 4 blocks/CU.
//
// ws layout (bytes):
//   M    @ 0          bf16 4096x6144
//   Y    @ 50331648   fp32 4096x512
//   sums @ 58720256   2 floats
//   bids @ 58720320   4x1024 int
//   Wc   @ 58736768   canonical bf16 weights

typedef __attribute__((ext_vector_type(8))) short bf16x8;   // 8 bf16 = 4 VGPR
typedef __attribute__((ext_vector_type(4))) float f32x4;    // MFMA C/D

struct PtrTab { const void* p[16]; };

// Wc element offsets (multiples of 8 -> 16B-aligned rows)
enum : int {
  O_WQT = 0,        // [96][104]  W^T padded
  O_BQ  = 9984,
  O_WKT = 10080,
  O_BK  = 20064,
  O_WVT = 20160,
  O_BV  = 30144,
  O_ER  = 30240,    // [64][32]
  O_W1T = 32288,    // [384][104]
  O_B1  = 72224,
  O_W2C = 72608,    // [12][96][40]  W2^T k-chunks of 32, padded to 40
  O_B2  = 118688,
  O_WET = 118784    // [8 nt][96 kt][64 n'][64 k']
};

__device__ __forceinline__ float b2f(__hip_bfloat16 v) { return __bfloat162float(v); }
__device__ __forceinline__ __hip_bfloat16 f2b(float v) { return __float2bfloat16(v); }

__global__ void convert_kernel(PtrTab tab, __hip_bfloat16* __restrict__ Wc) {
    const int g = blockIdx.x * 256 + threadIdx.x;
    const int stride = gridDim.x * 256;
    const float* Wq = (const float*)tab.p[3];
    const float* bq = (const float*)tab.p[4];
    const float* Wk = (const float*)tab.p[5];
    const float* bk = (const float*)tab.p[6];
    const float* Wv = (const float*)tab.p[7];
    const float* bv = (const float*)tab.p[8];
    const float* Er = (const float*)tab.p[9];
    const float* W1 = (const float*)tab.p[10];
    const float* b1 = (const float*)tab.p[11];
    const float* W2 = (const float*)tab.p[12];
    const float* b2 = (const float*)tab.p[13];

    for (int t = 0; t < 3; ++t) {
        const float* W = (t == 0 ? Wq : t == 1 ? Wk : Wv);
        __hip_bfloat16* d = Wc + (t == 0 ? O_WQT : t == 1 ? O_WKT : O_WVT);
        for (int i = g; i < 9984; i += stride) {
            int j = i / 104, c = i - j * 104;
            d[i] = (c < 96) ? f2b(W[c * 96 + j]) : f2b(0.0f);
        }
    }
    for (int i = g; i < 96; i += stride) {
        Wc[O_BQ + i] = f2b(bq[i]);
        Wc[O_BK + i] = f2b(bk[i]);
        Wc[O_BV + i] = f2b(bv[i]);
        Wc[O_B2 + i] = f2b(b2[i]);
    }
    for (int i = g; i < 2048; i += stride) Wc[O_ER + i] = f2b(Er[i]);
    for (int i = g; i < 39936; i += stride) {
        int j = i / 104, c = i - j * 104;
        Wc[O_W1T + i] = (c < 96) ? f2b(W1[c * 384 + j]) : f2b(0.0f);
    }
    for (int i = g; i < 384; i += stride) Wc[O_B1 + i] = f2b(b1[i]);
    for (int i = g; i < 46080; i += stride) {
        int kc = i / 3840, r = i - kc * 3840;
        int n = r / 40, kk = r - n * 40;
        Wc[O_W2C + i] = (kk < 32) ? f2b(W2[(kc * 32 + kk) * 96 + n]) : f2b(0.0f);
    }
}

// We (6144x512 fp32) -> blocked WeT: [nt][kt][n'][k'] = We[kt*64+k'][nt*64+n']
__global__ __launch_bounds__(256) void transpose_we_kernel(
    const float* __restrict__ We, __hip_bfloat16* __restrict__ Wc)
{
    __shared__ __hip_bfloat16 tile[64][65];
    const int kt = blockIdx.x, nt = blockIdx.y, tid = threadIdx.x;
    const int k0 = kt * 64, n0 = nt * 64;
    for (int e = tid; e < 4096; e += 256) {
        int kk = e >> 6, nn = e & 63;
        tile[nn][kk] = f2b(We[(size_t)(k0 + kk) * 512 + n0 + nn]);
    }
    __syncthreads();
    __hip_bfloat16* dst = Wc + O_WET + ((size_t)nt * 96 + kt) * 4096;
    for (int e = tid; e < 4096; e += 256)
        dst[e] = tile[e >> 6][e & 63];
}

// Fragment layouts (HW-verified): A: m=lane&15, k=quad*8+j; B from B^T same;
// C/D: col=lane&15, row=quad*4+reg.
__global__ __launch_bounds__(256) void attn_ffn_kernel(
    const float* __restrict__ x, const __hip_bfloat16* __restrict__ Wc,
    __hip_bfloat16* __restrict__ M)
{
    const int n = blockIdx.x, tid = threadIdx.x;
    const int w = tid >> 6, lane = tid & 63, quad = lane >> 4, ln = lane & 15;

    // LDS layout (50,432 B -> 3 blocks/CU); wb no longer overlaps kS (R6 bug fix)
    __shared__ __align__(16) char smem[50432];
    __hip_bfloat16* xs  = (__hip_bfloat16*)(smem);          // [64][104] x / att
    __hip_bfloat16* wb  = (__hip_bfloat16*)(smem + 13312);  // 9984 B weight stage
    __hip_bfloat16* PB  = (__hip_bfloat16*)(smem + 13312);  // [64][72] (phase B only)
    __hip_bfloat16* wb2 = (__hip_bfloat16*)(smem + 13312);  // [96][40] FFN2 stage
    __hip_bfloat16* kS  = (__hip_bfloat16*)(smem + 23296);  // [64][104] Qscr / K
    __hip_bfloat16* vT  = (__hip_bfloat16*)(smem + 36608);  // [96][72] V^T
    __hip_bfloat16* hid = (__hip_bfloat16*)(smem + 23296);  // [64][200] (phase C)

    // stage x transposed: xs[l=f][d=s] = x[n*6144 + s*64 + f] (float4 reads)
    const float4* xb4 = (const float4*)(x + (size_t)n * 6144);
    for (int e4 = tid; e4 < 1536; e4 += 256) {
        float4 v = xb4[e4];
        int e = e4 * 4, d = e >> 6, l = e & 63;
        xs[(l + 0) * 104 + d] = f2b(v.x);
        xs[(l + 1) * 104 + d] = f2b(v.y);
        xs[(l + 2) * 104 + d] = f2b(v.z);
        xs[(l + 3) * 104 + d] = f2b(v.w);
    }
    __syncthreads();

    const int rowb = 16 * w + quad * 4;
    const f32x4 z4 = {0.f, 0.f, 0.f, 0.f};
    bf16x8 aqr[3];                                          // Q A-frags (regs)

    // ---------- phase A: Q/K/V = xs(64x96) @ W + b (LDS-staged W^T) ----------
    for (int t = 0; t < 3; ++t) {
        const __hip_bfloat16* WT = Wc + (t == 0 ? O_WQT : t == 1 ? O_WKT : O_WVT);
        const __hip_bfloat16* bt = Wc + (t == 0 ? O_BQ : t == 1 ? O_BK : O_BV);
        for (int half = 0; half < 2; ++half) {
            __syncthreads();                                // wb consumers done
            {   // flat copy 48x104 el
                const bf16x8* src = (const bf16x8*)(WT + half * 4992);
                bf16x8* dst = (bf16x8*)wb;
                for (int e = tid; e < 624; e += 256) dst[e] = src[e];
            }
            __syncthreads();
            f32x4 acc[3] = {z4, z4, z4};
            #pragma unroll
            for (int ks = 0; ks < 3; ++ks) {
                bf16x8 a = *(const bf16x8*)(xs + (16 * w + ln) * 104 + ks * 32 + quad * 8);
                #pragma unroll
                for (int ct = 0; ct < 3; ++ct) {
                    bf16x8 b = *(const bf16x8*)(wb + (ct * 16 + ln) * 104 + ks * 32 + quad * 8);
                    acc[ct] = __builtin_amdgcn_mfma_f32_16x16x32_bf16(a, b, acc[ct], 0, 0, 0);
                }
            }
            const int j0 = half * 48;
            #pragma unroll
            for (int ct = 0; ct < 3; ++ct) {
                int col = j0 + ct * 16 + ln;
                float bb = b2f(bt[col]);
                if (t < 2) {                                // Q scratch / K (wave-local rows)
                    #pragma unroll
                    for (int r = 0; r < 4; ++r)
                        kS[(rowb + r) * 104 + col] = f2b(acc[ct][r] + bb);
                } else {
                    #pragma unroll
                    for (int r = 0; r < 4; ++r)
                        vT[col * 72 + (rowb + r)] = f2b(acc[ct][r] + bb);
                }
            }
            if (t == 0 && half == 1) {                      // own-wave rows -> no barrier
                #pragma unroll
                for (int h = 0; h < 3; ++h)
                    aqr[h] = *(const bf16x8*)(kS + (16 * w + ln) * 104 + h * 32 + quad * 8);
            }
        }
    }

    bf16x8 erf[4];                                          // Er B-frags (global, cached)
    #pragma unroll
    for (int tn = 0; tn < 4; ++tn)
        erf[tn] = *(const bf16x8*)(Wc + O_ER + (16 * tn + ln) * 32 + quad * 8);
    __syncthreads();                                        // K/V visible; wb free

    // ---------- phase B: MFMA attention (barrier-free) ----------
    for (int h = 0; h < 3; ++h) {
        const int c0 = h * 32;
        bf16x8 aq = aqr[h];
        #pragma unroll
        for (int tn = 0; tn < 4; ++tn) {                    // Qer -> PB (own rows)
            f32x4 q4 = __builtin_amdgcn_mfma_f32_16x16x32_bf16(aq, erf[tn], z4, 0, 0, 0);
            #pragma unroll
            for (int r = 0; r < 4; ++r)
                PB[(rowb + r) * 72 + 16 * tn + ln] = f2b(q4[r]);
        }
        float sco[4][4];
        #pragma unroll
        for (int tn = 0; tn < 4; ++tn) {
            bf16x8 kf = *(const bf16x8*)(kS + (16 * tn + ln) * 104 + c0 + quad * 8);
            f32x4 s1 = __builtin_amdgcn_mfma_f32_16x16x32_bf16(aq, kf, z4, 0, 0, 0);
            #pragma unroll
            for (int r = 0; r < 4; ++r) sco[tn][r] = s1[r];
        }
        #pragma unroll
        for (int tn = 0; tn < 4; ++tn)
            #pragma unroll
            for (int r = 0; r < 4; ++r) {
                int row = rowb + r, col = 16 * tn + ln;
                if (col <= row)
                    sco[tn][r] = (sco[tn][r] + b2f(PB[row * 72 + col + 63 - row]))
                                 * 0.17677669529663687f;
                else
                    sco[tn][r] = -3.0e38f;
            }
        float mx[4], sm[4];
        #pragma unroll
        for (int r = 0; r < 4; ++r) {
            float m0 = fmaxf(fmaxf(sco[0][r], sco[1][r]), fmaxf(sco[2][r], sco[3][r]));
            #pragma unroll
            for (int d = 1; d < 16; d <<= 1) m0 = fmaxf(m0, __shfl_xor(m0, d, 64));
            mx[r] = m0;
        }
        #pragma unroll
        for (int tn = 0; tn < 4; ++tn)
            #pragma unroll
            for (int r = 0; r < 4; ++r) sco[tn][r] = __expf(sco[tn][r] - mx[r]);
        #pragma unroll
        for (int r = 0; r < 4; ++r) {
            float s0 = sco[0][r] + sco[1][r] + sco[2][r] + sco[3][r];
            #pragma unroll
            for (int d = 1; d < 16; d <<= 1) s0 += __shfl_xor(s0, d, 64);
            sm[r] = 1.0f / s0;
        }
        #pragma unroll
        for (int tn = 0; tn < 4; ++tn)
            #pragma unroll
            for (int r = 0; r < 4; ++r)
                PB[(rowb + r) * 72 + 16 * tn + ln] = f2b(sco[tn][r] * sm[r]);
        f32x4 oacc[2] = {z4, z4};
        #pragma unroll
        for (int ks2 = 0; ks2 < 2; ++ks2) {
            bf16x8 pa = *(const bf16x8*)(PB + (16 * w + ln) * 72 + ks2 * 32 + quad * 8);
            #pragma unroll
            for (int t2 = 0; t2 < 2; ++t2) {
                bf16x8 vb = *(const bf16x8*)(vT + (c0 + 16 * t2 + ln) * 72 + ks2 * 32 + quad * 8);
                oacc[t2] = __builtin_amdgcn_mfma_f32_16x16x32_bf16(pa, vb, oacc[t2], 0, 0, 0);
            }
        }
        #pragma unroll
        for (int t2 = 0; t2 < 2; ++t2)
            #pragma unroll
            for (int r = 0; r < 4; ++r)
                xs[(rowb + r) * 104 + c0 + 16 * t2 + ln] = f2b(oacc[t2][r]);
    }

    // ---------- phase C: FFN (LDS-staged W1^T / W2 chunks) ----------
    f32x4 acc2[6] = {z4, z4, z4, z4, z4, z4};
    for (int jh = 0; jh < 2; ++jh) {
        for (int cc = 0; cc < 4; ++cc) {
            const int j0g = jh * 192 + cc * 48;
            __syncthreads();                               // wb/PB consumers done
            {
                const bf16x8* src = (const bf16x8*)(Wc + O_W1T + j0g * 104);
                bf16x8* dst = (bf16x8*)wb;
                for (int e = tid; e < 624; e += 256) dst[e] = src[e];
            }
            __syncthreads();
            f32x4 a1[3] = {z4, z4, z4};
            #pragma unroll
            for (int ks = 0; ks < 3; ++ks) {
                bf16x8 a = *(const bf16x8*)(xs + (16 * w + ln) * 104 + ks * 32 + quad * 8);
                #pragma unroll
                for (int ct = 0; ct < 3; ++ct) {
                    bf16x8 b = *(const bf16x8*)(wb + (ct * 16 + ln) * 104 + ks * 32 + quad * 8);
                    a1[ct] = __builtin_amdgcn_mfma_f32_16x16x32_bf16(a, b, a1[ct], 0, 0, 0);
                }
            }
            #pragma unroll
            for (int ct = 0; ct < 3; ++ct) {
                int colg = j0g + ct * 16 + ln;
                int coll = cc * 48 + ct * 16 + ln;
                float bb = b2f(Wc[O_B1 + colg]);
                #pragma unroll
                for (int r = 0; r < 4; ++r)
                    hid[(rowb + r) * 200 + coll] = f2b(fmaxf(a1[ct][r] + bb, 0.f));
            }
        }
        for (int kc = 0; kc < 6; ++kc) {                    // hid read: own-wave rows
            const int kcg = jh * 6 + kc;
            __syncthreads();
            {
                const bf16x8* src = (const bf16x8*)(Wc + O_W2C + kcg * 3840);
                bf16x8* dst = (bf16x8*)wb2;
                for (int e = tid; e < 480; e += 256) dst[e] = src[e];
            }
            __syncthreads();
            bf16x8 a = *(const bf16x8*)(hid + (16 * w + ln) * 200 + kc * 32 + quad * 8);
            #pragma unroll
            for (int ct = 0; ct < 6; ++ct) {
                bf16x8 b = *(const bf16x8*)(wb2 + (ct * 16 + ln) * 40 + quad * 8);
                acc2[ct] = __builtin_amdgcn_mfma_f32_16x16x32_bf16(a, b, acc2[ct], 0, 0, 0);
            }
        }
    }

    // epilogue: M[n][d*64 + l] = acc2 + b2[d], packed 8B stores
    __hip_bfloat16* Mg = M + (size_t)n * 6144;
    #pragma unroll
    for (int ct = 0; ct < 6; ++ct) {
        int d = ct * 16 + ln;
        float bb = b2f(Wc[O_B2 + d]);
        union { __hip_bfloat16 h4[4]; uint2 u; } pk;
        #pragma unroll
        for (int r = 0; r < 4; ++r) pk.h4[r] = f2b(acc2[ct][r] + bb);
        *(uint2*)((char*)Mg + (size_t)(d * 64 + rowb) * 2) = pk.u;
    }
}

// Y = A(4096x6144) @ We + be. A and B tiles double-buffered in LDS with
// register prefetch; 1 barrier/iter; B from blocked WeT (flat copy, no
// transpose); LDS 36,864 B -> 4 blocks/CU.
__global__ __launch_bounds__(256) void gemm_kernel(
    const __hip_bfloat16* __restrict__ A,    // 4096 x 6144 (M workspace)
    const __hip_bfloat16* __restrict__ Wc,
    const float* __restrict__ be,            // fp32 bias (512)
    float* __restrict__ Y)                   // 4096 x 512
{
    __shared__ __align__(16) __hip_bfloat16 As[2][64 * 72];
    __shared__ __align__(16) __hip_bfloat16 Bs[2][64 * 72];
    const int row0 = blockIdx.x * 64, nt = blockIdx.y, col0 = nt * 64;
    const int tid = threadIdx.x;
    const int w = tid >> 6, lane = tid & 63, quad = lane >> 4, ln = lane & 15;
    // each thread stages elements e0=tid, e1=tid+256 of the 512-vector tile
    const int r0 = tid >> 3, c0_ = (tid & 7) * 8;
    const int r1 = r0 + 32,  c1_ = c0_;
    const size_t abase0 = (size_t)(row0 + r0) * 6144 + c0_;
    const size_t abase1 = (size_t)(row0 + r1) * 6144 + c1_;
    const __hip_bfloat16* Bsrc = Wc + O_WET + (size_t)nt * 96 * 4096;
    const size_t bbase0 = (size_t)r0 * 64 + c0_;
    const size_t bbase1 = (size_t)r1 * 64 + c1_;

    const f32x4 z4 = {0.f, 0.f, 0.f, 0.f};
    f32x4 acc[4] = {z4, z4, z4, z4};

    bf16x8 pa0 = *(const bf16x8*)(A + abase0);
    bf16x8 pa1 = *(const bf16x8*)(A + abase1);
    bf16x8 pb0 = *(const bf16x8*)(Bsrc + bbase0);
    bf16x8 pb1 = *(const bf16x8*)(Bsrc + bbase1);
    *(bf16x8*)(&As[0][r0 * 72 + c0_]) = pa0;
    *(bf16x8*)(&As[0][r1 * 72 + c1_]) = pa1;
    *(bf16x8*)(&Bs[0][r0 * 72 + c0_]) = pb0;
    *(bf16x8*)(&Bs[0][r1 * 72 + c1_]) = pb1;
    __syncthreads();

    for (int kt = 0; kt < 96; ++kt) {
        const int cur = kt & 1;
        if (kt < 95) {                                      // prefetch next tiles
            pa0 = *(const bf16x8*)(A + abase0 + (kt + 1) * 64);
            pa1 = *(const bf16x8*)(A + abase1 + (kt + 1) * 64);
            pb0 = *(const bf16x8*)(Bsrc + (size_t)(kt + 1) * 4096 + bbase0);
            pb1 = *(const bf16x8*)(Bsrc + (size_t)(kt + 1) * 4096 + bbase1);
        }
        #pragma unroll
        for (int ks = 0; ks < 2; ++ks) {
            bf16x8 a = *(const bf16x8*)(&As[cur][(16 * w + ln) * 72 + ks * 32 + quad * 8]);
            #pragma unroll
            for (int tn = 0; tn < 4; ++tn) {
                bf16x8 b = *(const bf16x8*)(&Bs[cur][(16 * tn + ln) * 72 + ks * 32 + quad * 8]);
                acc[tn] = __builtin_amdgcn_mfma_f32_16x16x32_bf16(a, b, acc[tn], 0, 0, 0);
            }
        }
        if (kt < 95) {
            *(bf16x8*)(&As[cur ^ 1][r0 * 72 + c0_]) = pa0;
            *(bf16x8*)(&As[cur ^ 1][r1 * 72 + c1_]) = pa1;
            *(bf16x8*)(&Bs[cur ^ 1][r0 * 72 + c0_]) = pb0;
            *(bf16x8*)(&Bs[cur ^ 1][r1 * 72 + c1_]) = pb1;
        }
        __syncthreads();
    }
    #pragma unroll
    for (int tn = 0; tn < 4; ++tn) {
        int col = col0 + 16 * tn + ln;
        float bb = be[col];
        #pragma unroll
        for (int r = 0; r < 4; ++r)
            Y[(size_t)(row0 + 16 * w + quad * 4 + r) * 512 + col] = acc[tn][r] + bb;
    }
}

__global__ void zero_kernel(float* __restrict__ sums) {
    if (threadIdx.x < 2) sums[threadIdx.x] = 0.f;
}

__global__ __launch_bounds__(256) void reduce_kernel(const float* __restrict__ Y,
                                                     float* __restrict__ sums) {
    float s = 0.f, s2 = 0.f;
    for (size_t i = (size_t)blockIdx.x * 256 + threadIdx.x; i < 2097152; i += (size_t)gridDim.x * 256) {
        float v = Y[i];
        s += v; s2 += v * v;
    }
    #pragma unroll
    for (int off = 1; off < 64; off <<= 1) {
        s  += __shfl_xor(s, off, 64);
        s2 += __shfl_xor(s2, off, 64);
    }
    __shared__ float r1[4], r2[4];
    const int lane = threadIdx.x & 63, wv = threadIdx.x >> 6;
    if (lane == 0) { r1[wv] = s; r2[wv] = s2; }
    __syncthreads();
    if (threadIdx.x == 0) {
        atomicAdd(&sums[0], r1[0] + r1[1] + r1[2] + r1[3]);
        atomicAdd(&sums[1], r2[0] + r2[1] + r2[2] + r2[3]);
    }
}

__global__ void segid_kernel(const int* __restrict__ o_enc, int* __restrict__ bids) {
    int b = threadIdx.x;
    if (b < 4) {
        const int* o = o_enc + b * 1024;
        int* bid = bids + b * 1024;
        int run = 0;
        int off = o[0];
        for (int t = 0; t < 1024; ++t) { run += o[t]; bid[t] = run - off; }
    }
}

__global__ __launch_bounds__(256) void final_kernel(
    const float* __restrict__ Y, const int* __restrict__ bids,
    const float* __restrict__ sums, const float* __restrict__ r_enc,
    float* __restrict__ out)
{
    const int bt = blockIdx.x;
    const int b = bt >> 10, t = bt & 1023;
    const float mu = sums[0] * (1.0f / 2097152.0f);
    const float var = sums[1] * (1.0f / 2097152.0f) - mu * mu;
    const float rstd = rsqrtf(var + 1e-8f);
    const int* bid = bids + b * 1024;
    const int my = bid[t];
    const bool is_start = (t == 0) || (bid[t - 1] != my);
    int t2 = t + 1;
    float invc = 0.f;
    if (is_start) {
        while (t2 < 1024 && bid[t2] == my) ++t2;
        invc = 1.0f / (float)(t2 - t);
    }
    for (int e = threadIdx.x; e < 512; e += 256) {
        const size_t base = (size_t)bt * 512 + e;
        float res = (Y[base] - mu) * rstd + r_enc[base];
        if (is_start) {
            float s = 0.f;
            for (int tt = t; tt < t2; ++tt)
                s += (Y[((size_t)(b * 1024 + tt)) * 512 + e] - mu) * rstd;
            res += s * invc;
        }
        out[base] = res;
    }
}

extern "C" void kernel_launch(void* const* d_in, const int* in_sizes, int n_in,
                              void* d_out, int out_size, void* d_ws, size_t ws_size,
                              hipStream_t stream) {
    PtrTab tab;
    for (int i = 0; i < 16; ++i) tab.p[i] = d_in[i];

    char* ws = (char*)d_ws;
    __hip_bfloat16* M  = (__hip_bfloat16*)ws;
    float* Y           = (float*)(ws + 50331648);
    float* sums        = (float*)(ws + 58720256);
    int*   bids        = (int*)(ws + 58720320);
    __hip_bfloat16* Wc = (__hip_bfloat16*)(ws + 58736768);

    convert_kernel<<<128, 256, 0, stream>>>(tab, Wc);
    transpose_we_kernel<<<dim3(96, 8), 256, 0, stream>>>((const float*)d_in[14], Wc);
    attn_ffn_kernel<<<4096, 256, 0, stream>>>((const float*)d_in[0], Wc, M);
    gemm_kernel<<<dim3(64, 8), 256, 0, stream>>>(M, Wc, (const float*)d_in[15], Y);
    zero_kernel<<<1, 64, 0, stream>>>(sums);
    reduce_kernel<<<512, 256, 0, stream>>>(Y, sums);
    segid_kernel<<<1, 64, 0, stream>>>((const int*)d_in[1], bids);
    final_kernel<<<4096, 256, 0, stream>>>(Y, bids, sums, (const float*)d_in[2], (float*)d_out);
}

// Round 9
// 483.222 us; speedup vs baseline: 1.4542x; 1.0858x over previous
//
#include <hip/hip_runtime.h>
#include <hip/hip_bf16.h>

// DecoderInputEmbedding — B=4, T=1024, F=6144 (SW=96 x FB=64), EMB=512, H=3, dh=32.
// All inputs fp32 (o_enc int32), output fp32. Internals bf16 (2%-rel threshold).
// R9: attn_ffn weight stages software-pipelined (register prefetch of next
// stage during current MFMA window; same barriers/LDS/occupancy); gemm
// split-K=2 -> 1024 blocks (4/CU, 16 waves), atomicAdd into bias-init Y.
//
// ws layout (bytes):
//   M    @ 0          bf16 4096x6144
//   Y    @ 50331648   fp32 4096x512   (bias-initialized; gemm atomicAdds)
//   sums @ 58720256   2 floats
//   bids @ 58720320   4x1024 int
//   Wc   @ 58736768   canonical bf16 weights

typedef __attribute__((ext_vector_type(8))) short bf16x8;   // 8 bf16 = 4 VGPR
typedef __attribute__((ext_vector_type(4))) float f32x4;    // MFMA C/D

struct PtrTab { const void* p[16]; };

// Wc element offsets (multiples of 8 -> 16B-aligned rows)
enum : int {
  O_WQT = 0,        // [96][104]  W^T padded
  O_BQ  = 9984,
  O_WKT = 10080,
  O_BK  = 20064,
  O_WVT = 20160,
  O_BV  = 30144,
  O_ER  = 30240,    // [64][32]
  O_W1T = 32288,    // [384][104]
  O_B1  = 72224,
  O_W2C = 72608,    // [12][96][40]  W2^T k-chunks of 32, padded to 40
  O_B2  = 118688,
  O_WET = 118784    // [8 nt][96 kt][64 n'][64 k']
};

__device__ __forceinline__ float b2f(__hip_bfloat16 v) { return __bfloat162float(v); }
__device__ __forceinline__ __hip_bfloat16 f2b(float v) { return __float2bfloat16(v); }

__global__ void convert_kernel(PtrTab tab, __hip_bfloat16* __restrict__ Wc) {
    const int g = blockIdx.x * 256 + threadIdx.x;
    const int stride = gridDim.x * 256;
    const float* Wq = (const float*)tab.p[3];
    const float* bq = (const float*)tab.p[4];
    const float* Wk = (const float*)tab.p[5];
    const float* bk = (const float*)tab.p[6];
    const float* Wv = (const float*)tab.p[7];
    const float* bv = (const float*)tab.p[8];
    const float* Er = (const float*)tab.p[9];
    const float* W1 = (const float*)tab.p[10];
    const float* b1 = (const float*)tab.p[11];
    const float* W2 = (const float*)tab.p[12];
    const float* b2 = (const float*)tab.p[13];

    for (int t = 0; t < 3; ++t) {
        const float* W = (t == 0 ? Wq : t == 1 ? Wk : Wv);
        __hip_bfloat16* d = Wc + (t == 0 ? O_WQT : t == 1 ? O_WKT : O_WVT);
        for (int i = g; i < 9984; i += stride) {
            int j = i / 104, c = i - j * 104;
            d[i] = (c < 96) ? f2b(W[c * 96 + j]) : f2b(0.0f);
        }
    }
    for (int i = g; i < 96; i += stride) {
        Wc[O_BQ + i] = f2b(bq[i]);
        Wc[O_BK + i] = f2b(bk[i]);
        Wc[O_BV + i] = f2b(bv[i]);
        Wc[O_B2 + i] = f2b(b2[i]);
    }
    for (int i = g; i < 2048; i += stride) Wc[O_ER + i] = f2b(Er[i]);
    for (int i = g; i < 39936; i += stride) {
        int j = i / 104, c = i - j * 104;
        Wc[O_W1T + i] = (c < 96) ? f2b(W1[c * 384 + j]) : f2b(0.0f);
    }
    for (int i = g; i < 384; i += stride) Wc[O_B1 + i] = f2b(b1[i]);
    for (int i = g; i < 46080; i += stride) {
        int kc = i / 3840, r = i - kc * 3840;
        int n = r / 40, kk = r - n * 40;
        Wc[O_W2C + i] = (kk < 32) ? f2b(W2[(kc * 32 + kk) * 96 + n]) : f2b(0.0f);
    }
}

// We (6144x512 fp32) -> blocked WeT: [nt][kt][n'][k'] = We[kt*64+k'][nt*64+n']
__global__ __launch_bounds__(256) void transpose_we_kernel(
    const float* __restrict__ We, __hip_bfloat16* __restrict__ Wc)
{
    __shared__ __hip_bfloat16 tile[64][65];
    const int kt = blockIdx.x, nt = blockIdx.y, tid = threadIdx.x;
    const int k0 = kt * 64, n0 = nt * 64;
    for (int e = tid; e < 4096; e += 256) {
        int kk = e >> 6, nn = e & 63;
        tile[nn][kk] = f2b(We[(size_t)(k0 + kk) * 512 + n0 + nn]);
    }
    __syncthreads();
    __hip_bfloat16* dst = Wc + O_WET + ((size_t)nt * 96 + kt) * 4096;
    for (int e = tid; e < 4096; e += 256)
        dst[e] = tile[e >> 6][e & 63];
}

// Y[i] = be[i & 511]  (bias pre-init; gemm atomicAdds partial sums)
__global__ __launch_bounds__(256) void ybias_kernel(const float* __restrict__ be,
                                                    float* __restrict__ Y) {
    const int i = blockIdx.x * 256 + threadIdx.x;       // float4 index, 524288 total
    ((float4*)Y)[i] = ((const float4*)be)[i & 127];
}

// Fragment layouts (HW-verified): A: m=lane&15, k=quad*8+j; B from B^T same;
// C/D: col=lane&15, row=quad*4+reg.
__global__ __launch_bounds__(256) void attn_ffn_kernel(
    const float* __restrict__ x, const __hip_bfloat16* __restrict__ Wc,
    __hip_bfloat16* __restrict__ M)
{
    const int n = blockIdx.x, tid = threadIdx.x;
    const int w = tid >> 6, lane = tid & 63, quad = lane >> 4, ln = lane & 15;

    // LDS layout (50,432 B -> 3 blocks/CU)
    __shared__ __align__(16) char smem[50432];
    __hip_bfloat16* xs  = (__hip_bfloat16*)(smem);          // [64][104] x / att
    __hip_bfloat16* wb  = (__hip_bfloat16*)(smem + 13312);  // 9984 B weight stage
    __hip_bfloat16* PB  = (__hip_bfloat16*)(smem + 13312);  // [64][72] (phase B only)
    __hip_bfloat16* kS  = (__hip_bfloat16*)(smem + 23296);  // [64][104] Qscr / K
    __hip_bfloat16* vT  = (__hip_bfloat16*)(smem + 36608);  // [96][72] V^T
    __hip_bfloat16* hid = (__hip_bfloat16*)(smem + 23296);  // [64][200] (phase C)

    // ---- software-pipelined weight staging: registers hold NEXT stage ----
    bf16x8 pf0, pf1, pf2;
    // prefetch stage A0 (Wq half 0, 624 vecs) before x staging
    {
        const bf16x8* src = (const bf16x8*)(Wc + O_WQT);
        pf0 = src[tid];
        pf1 = src[tid + 256];                       // 256..511 < 624
        if (tid + 512 < 624) pf2 = src[tid + 512];
    }

    // stage x transposed: xs[l=f][d=s] = x[n*6144 + s*64 + f] (float4 reads)
    const float4* xb4 = (const float4*)(x + (size_t)n * 6144);
    for (int e4 = tid; e4 < 1536; e4 += 256) {
        float4 v = xb4[e4];
        int e = e4 * 4, d = e >> 6, l = e & 63;
        xs[(l + 0) * 104 + d] = f2b(v.x);
        xs[(l + 1) * 104 + d] = f2b(v.y);
        xs[(l + 2) * 104 + d] = f2b(v.z);
        xs[(l + 3) * 104 + d] = f2b(v.w);
    }
    __syncthreads();

    const int rowb = 16 * w + quad * 4;
    const f32x4 z4 = {0.f, 0.f, 0.f, 0.f};
    bf16x8 aqr[3];                                          // Q A-frags (regs)

    // ---------- phase A: Q/K/V = xs(64x96) @ W + b ----------
    for (int t = 0; t < 3; ++t) {
        const __hip_bfloat16* bt = Wc + (t == 0 ? O_BQ : t == 1 ? O_BK : O_BV);
        for (int half = 0; half < 2; ++half) {
            __syncthreads();                                // wb consumers done
            {   // write prefetched stage, then issue next-stage loads (624 vecs)
                bf16x8* dst = (bf16x8*)wb;
                dst[tid] = pf0;
                dst[tid + 256] = pf1;
                if (tid + 512 < 624) dst[tid + 512] = pf2;
                int noff;                                   // next stage offset
                if (half == 0)      noff = (t == 0 ? O_WQT : t == 1 ? O_WKT : O_WVT) + 4992;
                else if (t == 0)    noff = O_WKT;
                else if (t == 1)    noff = O_WVT;
                else                noff = O_W1T;           // first FFN1 stage
                const bf16x8* src = (const bf16x8*)(Wc + noff);
                pf0 = src[tid];
                pf1 = src[tid + 256];
                if (tid + 512 < 624) pf2 = src[tid + 512];
            }
            __syncthreads();
            f32x4 acc[3] = {z4, z4, z4};
            #pragma unroll
            for (int ks = 0; ks < 3; ++ks) {
                bf16x8 a = *(const bf16x8*)(xs + (16 * w + ln) * 104 + ks * 32 + quad * 8);
                #pragma unroll
                for (int ct = 0; ct < 3; ++ct) {
                    bf16x8 b = *(const bf16x8*)(wb + (ct * 16 + ln) * 104 + ks * 32 + quad * 8);
                    acc[ct] = __builtin_amdgcn_mfma_f32_16x16x32_bf16(a, b, acc[ct], 0, 0, 0);
                }
            }
            const int j0 = half * 48;
            #pragma unroll
            for (int ct = 0; ct < 3; ++ct) {
                int col = j0 + ct * 16 + ln;
                float bb = b2f(bt[col]);
                if (t < 2) {                                // Q scratch / K (wave-local rows)
                    #pragma unroll
                    for (int r = 0; r < 4; ++r)
                        kS[(rowb + r) * 104 + col] = f2b(acc[ct][r] + bb);
                } else {
                    #pragma unroll
                    for (int r = 0; r < 4; ++r)
                        vT[col * 72 + (rowb + r)] = f2b(acc[ct][r] + bb);
                }
            }
            if (t == 0 && half == 1) {                      // own-wave rows -> no barrier
                #pragma unroll
                for (int h = 0; h < 3; ++h)
                    aqr[h] = *(const bf16x8*)(kS + (16 * w + ln) * 104 + h * 32 + quad * 8);
            }
        }
    }

    bf16x8 erf[4];                                          // Er B-frags (global, cached)
    #pragma unroll
    for (int tn = 0; tn < 4; ++tn)
        erf[tn] = *(const bf16x8*)(Wc + O_ER + (16 * tn + ln) * 32 + quad * 8);
    __syncthreads();                                        // K/V visible; wb free

    // ---------- phase B: MFMA attention (barrier-free) ----------
    for (int h = 0; h < 3; ++h) {
        const int c0 = h * 32;
        bf16x8 aq = aqr[h];
        #pragma unroll
        for (int tn = 0; tn < 4; ++tn) {                    // Qer -> PB (own rows)
            f32x4 q4 = __builtin_amdgcn_mfma_f32_16x16x32_bf16(aq, erf[tn], z4, 0, 0, 0);
            #pragma unroll
            for (int r = 0; r < 4; ++r)
                PB[(rowb + r) * 72 + 16 * tn + ln] = f2b(q4[r]);
        }
        float sco[4][4];
        #pragma unroll
        for (int tn = 0; tn < 4; ++tn) {
            bf16x8 kf = *(const bf16x8*)(kS + (16 * tn + ln) * 104 + c0 + quad * 8);
            f32x4 s1 = __builtin_amdgcn_mfma_f32_16x16x32_bf16(aq, kf, z4, 0, 0, 0);
            #pragma unroll
            for (int r = 0; r < 4; ++r) sco[tn][r] = s1[r];
        }
        #pragma unroll
        for (int tn = 0; tn < 4; ++tn)
            #pragma unroll
            for (int r = 0; r < 4; ++r) {
                int row = rowb + r, col = 16 * tn + ln;
                if (col <= row)
                    sco[tn][r] = (sco[tn][r] + b2f(PB[row * 72 + col + 63 - row]))
                                 * 0.17677669529663687f;
                else
                    sco[tn][r] = -3.0e38f;
            }
        float mx[4], sm[4];
        #pragma unroll
        for (int r = 0; r < 4; ++r) {
            float m0 = fmaxf(fmaxf(sco[0][r], sco[1][r]), fmaxf(sco[2][r], sco[3][r]));
            #pragma unroll
            for (int d = 1; d < 16; d <<= 1) m0 = fmaxf(m0, __shfl_xor(m0, d, 64));
            mx[r] = m0;
        }
        #pragma unroll
        for (int tn = 0; tn < 4; ++tn)
            #pragma unroll
            for (int r = 0; r < 4; ++r) sco[tn][r] = __expf(sco[tn][r] - mx[r]);
        #pragma unroll
        for (int r = 0; r < 4; ++r) {
            float s0 = sco[0][r] + sco[1][r] + sco[2][r] + sco[3][r];
            #pragma unroll
            for (int d = 1; d < 16; d <<= 1) s0 += __shfl_xor(s0, d, 64);
            sm[r] = 1.0f / s0;
        }
        #pragma unroll
        for (int tn = 0; tn < 4; ++tn)
            #pragma unroll
            for (int r = 0; r < 4; ++r)
                PB[(rowb + r) * 72 + 16 * tn + ln] = f2b(sco[tn][r] * sm[r]);
        f32x4 oacc[2] = {z4, z4};
        #pragma unroll
        for (int ks2 = 0; ks2 < 2; ++ks2) {
            bf16x8 pa = *(const bf16x8*)(PB + (16 * w + ln) * 72 + ks2 * 32 + quad * 8);
            #pragma unroll
            for (int t2 = 0; t2 < 2; ++t2) {
                bf16x8 vb = *(const bf16x8*)(vT + (c0 + 16 * t2 + ln) * 72 + ks2 * 32 + quad * 8);
                oacc[t2] = __builtin_amdgcn_mfma_f32_16x16x32_bf16(pa, vb, oacc[t2], 0, 0, 0);
            }
        }
        #pragma unroll
        for (int t2 = 0; t2 < 2; ++t2)
            #pragma unroll
            for (int r = 0; r < 4; ++r)
                xs[(rowb + r) * 104 + c0 + 16 * t2 + ln] = f2b(oacc[t2][r]);
    }

    // ---------- phase C: FFN (pipelined W1^T / W2 chunk stages) ----------
    f32x4 acc2[6] = {z4, z4, z4, z4, z4, z4};
    for (int jh = 0; jh < 2; ++jh) {
        for (int cc = 0; cc < 4; ++cc) {                    // FFN1 stages (624 vecs)
            const int j0g = jh * 192 + cc * 48;
            __syncthreads();                                // wb/PB consumers done
            {
                bf16x8* dst = (bf16x8*)wb;
                dst[tid] = pf0;
                dst[tid + 256] = pf1;
                if (tid + 512 < 624) dst[tid + 512] = pf2;
                // next: cc<3 -> next W1 chunk (624); cc==3 -> first W2 chunk (480)
                int noff = (cc < 3) ? (O_W1T + (jh * 19968 + (cc + 1) * 4992))
                                    : (O_W2C + jh * 23040);
                int ncnt = (cc < 3) ? 624 : 480;
                const bf16x8* src = (const bf16x8*)(Wc + noff);
                pf0 = src[tid];
                if (tid + 256 < ncnt) pf1 = src[tid + 256];
                if (tid + 512 < ncnt) pf2 = src[tid + 512];
            }
            __syncthreads();
            f32x4 a1[3] = {z4, z4, z4};
            #pragma unroll
            for (int ks = 0; ks < 3; ++ks) {
                bf16x8 a = *(const bf16x8*)(xs + (16 * w + ln) * 104 + ks * 32 + quad * 8);
                #pragma unroll
                for (int ct = 0; ct < 3; ++ct) {
                    bf16x8 b = *(const bf16x8*)(wb + (ct * 16 + ln) * 104 + ks * 32 + quad * 8);
                    a1[ct] = __builtin_amdgcn_mfma_f32_16x16x32_bf16(a, b, a1[ct], 0, 0, 0);
                }
            }
            #pragma unroll
            for (int ct = 0; ct < 3; ++ct) {
                int colg = j0g + ct * 16 + ln;
                int coll = cc * 48 + ct * 16 + ln;
                float bb = b2f(Wc[O_B1 + colg]);
                #pragma unroll
                for (int r = 0; r < 4; ++r)
                    hid[(rowb + r) * 200 + coll] = f2b(fmaxf(a1[ct][r] + bb, 0.f));
            }
        }
        for (int kc = 0; kc < 6; ++kc) {                    // FFN2 stages (480 vecs)
            __syncthreads();
            {
                bf16x8* dst = (bf16x8*)wb;
                dst[tid] = pf0;
                if (tid + 256 < 480) dst[tid + 256] = pf1;
                // next: kc<5 -> next W2 chunk (480); kc==5,jh==0 -> W1 jh1 (624);
                //       kc==5,jh==1 -> none
                int ncnt = (kc < 5) ? 480 : (jh == 0 ? 624 : 0);
                if (ncnt) {
                    int noff = (kc < 5) ? (O_W2C + (jh * 6 + kc + 1) * 3840)
                                        : (O_W1T + 19968);
                    const bf16x8* src = (const bf16x8*)(Wc + noff);
                    pf0 = src[tid];
                    if (tid + 256 < ncnt) pf1 = src[tid + 256];
                    if (tid + 512 < ncnt) pf2 = src[tid + 512];
                }
            }
            __syncthreads();
            bf16x8 a = *(const bf16x8*)(hid + (16 * w + ln) * 200 + kc * 32 + quad * 8);
            #pragma unroll
            for (int ct = 0; ct < 6; ++ct) {
                bf16x8 b = *(const bf16x8*)(wb + (ct * 16 + ln) * 40 + quad * 8);
                acc2[ct] = __builtin_amdgcn_mfma_f32_16x16x32_bf16(a, b, acc2[ct], 0, 0, 0);
            }
        }
    }

    // epilogue: M[n][d*64 + l] = acc2 + b2[d], packed 8B stores
    __hip_bfloat16* Mg = M + (size_t)n * 6144;
    #pragma unroll
    for (int ct = 0; ct < 6; ++ct) {
        int d = ct * 16 + ln;
        float bb = b2f(Wc[O_B2 + d]);
        union { __hip_bfloat16 h4[4]; uint2 u; } pk;
        #pragma unroll
        for (int r = 0; r < 4; ++r) pk.h4[r] = f2b(acc2[ct][r] + bb);
        *(uint2*)((char*)Mg + (size_t)(d * 64 + rowb) * 2) = pk.u;
    }
}

// Y += A(64 rows x 3072 K-slice) @ WeT(64 cols). Split-K=2 -> 1024 blocks
// (4/CU, 16 waves/CU). A+B double-buffered LDS, register prefetch,
// 1 barrier/iter. Epilogue: atomicAdd into bias-initialized Y.
__global__ __launch_bounds__(256) void gemm_kernel(
    const __hip_bfloat16* __restrict__ A,    // 4096 x 6144 (M workspace)
    const __hip_bfloat16* __restrict__ Wc,
    float* __restrict__ Y)                   // 4096 x 512
{
    __shared__ __align__(16) __hip_bfloat16 As[2][64 * 72];
    __shared__ __align__(16) __hip_bfloat16 Bs[2][64 * 72];
    const int row0 = blockIdx.x * 64, nt = blockIdx.y, col0 = nt * 64;
    const int kh = blockIdx.z;
    const int tid = threadIdx.x;
    const int w = tid >> 6, lane = tid & 63, quad = lane >> 4, ln = lane & 15;
    const int r0 = tid >> 3, c0_ = (tid & 7) * 8;
    const int r1 = r0 + 32,  c1_ = c0_;
    const size_t abase0 = (size_t)(row0 + r0) * 6144 + kh * 3072 + c0_;
    const size_t abase1 = (size_t)(row0 + r1) * 6144 + kh * 3072 + c1_;
    const __hip_bfloat16* Bsrc = Wc + O_WET + ((size_t)nt * 96 + kh * 48) * 4096;
    const size_t bbase0 = (size_t)r0 * 64 + c0_;
    const size_t bbase1 = (size_t)r1 * 64 + c1_;

    const f32x4 z4 = {0.f, 0.f, 0.f, 0.f};
    f32x4 acc[4] = {z4, z4, z4, z4};

    bf16x8 pa0 = *(const bf16x8*)(A + abase0);
    bf16x8 pa1 = *(const bf16x8*)(A + abase1);
    bf16x8 pb0 = *(const bf16x8*)(Bsrc + bbase0);
    bf16x8 pb1 = *(const bf16x8*)(Bsrc + bbase1);
    *(bf16x8*)(&As[0][r0 * 72 + c0_]) = pa0;
    *(bf16x8*)(&As[0][r1 * 72 + c1_]) = pa1;
    *(bf16x8*)(&Bs[0][r0 * 72 + c0_]) = pb0;
    *(bf16x8*)(&Bs[0][r1 * 72 + c1_]) = pb1;
    __syncthreads();

    for (int kt = 0; kt < 48; ++kt) {
        const int cur = kt & 1;
        if (kt < 47) {                                      // prefetch next tiles
            pa0 = *(const bf16x8*)(A + abase0 + (kt + 1) * 64);
            pa1 = *(const bf16x8*)(A + abase1 + (kt + 1) * 64);
            pb0 = *(const bf16x8*)(Bsrc + (size_t)(kt + 1) * 4096 + bbase0);
            pb1 = *(const bf16x8*)(Bsrc + (size_t)(kt + 1) * 4096 + bbase1);
        }
        #pragma unroll
        for (int ks = 0; ks < 2; ++ks) {
            bf16x8 a = *(const bf16x8*)(&As[cur][(16 * w + ln) * 72 + ks * 32 + quad * 8]);
            #pragma unroll
            for (int tn = 0; tn < 4; ++tn) {
                bf16x8 b = *(const bf16x8*)(&Bs[cur][(16 * tn + ln) * 72 + ks * 32 + quad * 8]);
                acc[tn] = __builtin_amdgcn_mfma_f32_16x16x32_bf16(a, b, acc[tn], 0, 0, 0);
            }
        }
        if (kt < 47) {
            *(bf16x8*)(&As[cur ^ 1][r0 * 72 + c0_]) = pa0;
            *(bf16x8*)(&As[cur ^ 1][r1 * 72 + c1_]) = pa1;
            *(bf16x8*)(&Bs[cur ^ 1][r0 * 72 + c0_]) = pb0;
            *(bf16x8*)(&Bs[cur ^ 1][r1 * 72 + c1_]) = pb1;
        }
        __syncthreads();
    }
    #pragma unroll
    for (int tn = 0; tn < 4; ++tn) {
        int col = col0 + 16 * tn + ln;
        #pragma unroll
        for (int r = 0; r < 4; ++r)
            atomicAdd(&Y[(size_t)(row0 + 16 * w + quad * 4 + r) * 512 + col], acc[tn][r]);
    }
}

__global__ void zero_kernel(float* __restrict__ sums) {
    if (threadIdx.x < 2) sums[threadIdx.x] = 0.f;
}

__global__ __launch_bounds__(256) void reduce_kernel(const float* __restrict__ Y,
                                                     float* __restrict__ sums) {
    float s = 0.f, s2 = 0.f;
    for (size_t i = (size_t)blockIdx.x * 256 + threadIdx.x; i < 2097152; i += (size_t)gridDim.x * 256) {
        float v = Y[i];
        s += v; s2 += v * v;
    }
    #pragma unroll
    for (int off = 1; off < 64; off <<= 1) {
        s  += __shfl_xor(s, off, 64);
        s2 += __shfl_xor(s2, off, 64);
    }
    __shared__ float r1[4], r2[4];
    const int lane = threadIdx.x & 63, wv = threadIdx.x >> 6;
    if (lane == 0) { r1[wv] = s; r2[wv] = s2; }
    __syncthreads();
    if (threadIdx.x == 0) {
        atomicAdd(&sums[0], r1[0] + r1[1] + r1[2] + r1[3]);
        atomicAdd(&sums[1], r2[0] + r2[1] + r2[2] + r2[3]);
    }
}

__global__ void segid_kernel(const int* __restrict__ o_enc, int* __restrict__ bids) {
    int b = threadIdx.x;
    if (b < 4) {
        const int* o = o_enc + b * 1024;
        int* bid = bids + b * 1024;
        int run = 0;
        int off = o[0];
        for (int t = 0; t < 1024; ++t) { run += o[t]; bid[t] = run - off; }
    }
}

__global__ __launch_bounds__(256) void final_kernel(
    const float* __restrict__ Y, const int* __restrict__ bids,
    const float* __restrict__ sums, const float* __restrict__ r_enc,
    float* __restrict__ out)
{
    const int bt = blockIdx.x;
    const int b = bt >> 10, t = bt & 1023;
    const float mu = sums[0] * (1.0f / 2097152.0f);
    const float var = sums[1] * (1.0f / 2097152.0f) - mu * mu;
    const float rstd = rsqrtf(var + 1e-8f);
    const int* bid = bids + b * 1024;
    const int my = bid[t];
    const bool is_start = (t == 0) || (bid[t - 1] != my);
    int t2 = t + 1;
    float invc = 0.f;
    if (is_start) {
        while (t2 < 1024 && bid[t2] == my) ++t2;
        invc = 1.0f / (float)(t2 - t);
    }
    for (int e = threadIdx.x; e < 512; e += 256) {
        const size_t base = (size_t)bt * 512 + e;
        float res = (Y[base] - mu) * rstd + r_enc[base];
        if (is_start) {
            float s = 0.f;
            for (int tt = t; tt < t2; ++tt)
                s += (Y[((size_t)(b * 1024 + tt)) * 512 + e] - mu) * rstd;
            res += s * invc;
        }
        out[base] = res;
    }
}

extern "C" void kernel_launch(void* const* d_in, const int* in_sizes, int n_in,
                              void* d_out, int out_size, void* d_ws, size_t ws_size,
                              hipStream_t stream) {
    PtrTab tab;
    for (int i = 0; i < 16; ++i) tab.p[i] = d_in[i];

    char* ws = (char*)d_ws;
    __hip_bfloat16* M  = (__hip_bfloat16*)ws;
    float* Y           = (float*)(ws + 50331648);
    float* sums        = (float*)(ws + 58720256);
    int*   bids        = (int*)(ws + 58720320);
    __hip_bfloat16* Wc = (__hip_bfloat16*)(ws + 58736768);

    convert_kernel<<<128, 256, 0, stream>>>(tab, Wc);
    transpose_we_kernel<<<dim3(96, 8), 256, 0, stream>>>((const float*)d_in[14], Wc);
    ybias_kernel<<<2048, 256, 0, stream>>>((const float*)d_in[15], Y);
    attn_ffn_kernel<<<4096, 256, 0, stream>>>((const float*)d_in[0], Wc, M);
    gemm_kernel<<<dim3(64, 8, 2), 256, 0, stream>>>(M, Wc, Y);
    zero_kernel<<<1, 64, 0, stream>>>(sums);
    reduce_kernel<<<512, 256, 0, stream>>>(Y, sums);
    segid_kernel<<<1, 64, 0, stream>>>((const int*)d_in[1], bids);
    final_kernel<<<4096, 256, 0, stream>>>(Y, bids, sums, (const float*)d_in[2], (float*)d_out);
}

// Round 10
// 394.313 us; speedup vs baseline: 1.7820x; 1.2255x over previous
//
#include <hip/hip_runtime.h>
#include <hip/hip_bf16.h>

// DecoderInputEmbedding — B=4, T=1024, F=6144 (SW=96 x FB=64), EMB=512, H=3, dh=32.
// All inputs fp32 (o_enc int32), output fp32. Internals bf16 (2%-rel threshold).
// R10: attn_ffn phase-A/FFN2 weights as register fragments w/ stage prefetch
// (barriers 55->19); xs staged with b128 writes; vT packed stores; kernels
// fused 9->5 (prep = convert+transpose+zero; gemm += mean/var reduction;
// parallel segid scan).
//
// ws layout (bytes):
//   M    @ 0          bf16 4096x6144
//   Y    @ 50331648   fp32 4096x512
//   sums @ 58720256   2 floats
//   bids @ 58720320   4x1024 int
//   Wc   @ 58736768   canonical bf16 weights

typedef __attribute__((ext_vector_type(8))) short bf16x8;   // 8 bf16 = 4 VGPR
typedef __attribute__((ext_vector_type(4))) float f32x4;    // MFMA C/D

struct PtrTab { const void* p[16]; };

// Wc element offsets (multiples of 8 -> 16B-aligned rows). WQT/WKT/WVT spaced
// 10080 apart; biases spaced 10080 starting at 9984 (arithmetic indexing).
enum : int {
  O_WQT = 0,        // [96][104]  W^T padded
  O_BQ  = 9984,
  O_WKT = 10080,
  O_BK  = 20064,
  O_WVT = 20160,
  O_BV  = 30144,
  O_ER  = 30240,    // [64][32]
  O_W1T = 32288,    // [384][104]
  O_B1  = 72224,
  O_W2C = 72608,    // [12][96][40]  W2^T k-chunks of 32, padded to 40
  O_B2  = 118688,
  O_WET = 118784    // [8 nt][96 kt][64 n'][64 k']
};

__device__ __forceinline__ float b2f(__hip_bfloat16 v) { return __bfloat162float(v); }
__device__ __forceinline__ __hip_bfloat16 f2b(float v) { return __float2bfloat16(v); }

// prep: We transpose (per-block tile) + weight convert (grid-stride) + zero sums
__global__ __launch_bounds__(256) void prep_kernel(PtrTab tab,
                                                   __hip_bfloat16* __restrict__ Wc,
                                                   float* __restrict__ sums)
{
    __shared__ __hip_bfloat16 tile[64][65];
    const int bid = blockIdx.x, tid = threadIdx.x;
    // ---- We (6144x512) -> blocked WeT: [nt][kt][n'][k'] ----
    const int kt = bid % 96, nt = bid / 96;
    const float* We = (const float*)tab.p[14];
    const int k0 = kt * 64, n0 = nt * 64;
    for (int e = tid; e < 4096; e += 256) {
        int kk = e >> 6, nn = e & 63;
        tile[nn][kk] = f2b(We[(size_t)(k0 + kk) * 512 + n0 + nn]);
    }
    __syncthreads();
    __hip_bfloat16* dstT = Wc + O_WET + ((size_t)nt * 96 + kt) * 4096;
    for (int e = tid; e < 4096; e += 256) dstT[e] = tile[e >> 6][e & 63];

    // ---- converts (grid-stride over the whole grid) ----
    const int g = bid * 256 + tid;
    const int stride = gridDim.x * 256;
    const float* Wq = (const float*)tab.p[3];
    const float* bq = (const float*)tab.p[4];
    const float* Wk = (const float*)tab.p[5];
    const float* bk = (const float*)tab.p[6];
    const float* Wv = (const float*)tab.p[7];
    const float* bv = (const float*)tab.p[8];
    const float* Er = (const float*)tab.p[9];
    const float* W1 = (const float*)tab.p[10];
    const float* b1 = (const float*)tab.p[11];
    const float* W2 = (const float*)tab.p[12];
    const float* b2 = (const float*)tab.p[13];

    for (int t = 0; t < 3; ++t) {
        const float* W = (t == 0 ? Wq : t == 1 ? Wk : Wv);
        __hip_bfloat16* d = Wc + t * 10080;
        for (int i = g; i < 9984; i += stride) {
            int j = i / 104, c = i - j * 104;
            d[i] = (c < 96) ? f2b(W[c * 96 + j]) : f2b(0.0f);
        }
    }
    for (int i = g; i < 96; i += stride) {
        Wc[O_BQ + i] = f2b(bq[i]);
        Wc[O_BK + i] = f2b(bk[i]);
        Wc[O_BV + i] = f2b(bv[i]);
        Wc[O_B2 + i] = f2b(b2[i]);
    }
    for (int i = g; i < 2048; i += stride) Wc[O_ER + i] = f2b(Er[i]);
    for (int i = g; i < 39936; i += stride) {
        int j = i / 104, c = i - j * 104;
        Wc[O_W1T + i] = (c < 96) ? f2b(W1[c * 384 + j]) : f2b(0.0f);
    }
    for (int i = g; i < 384; i += stride) Wc[O_B1 + i] = f2b(b1[i]);
    for (int i = g; i < 46080; i += stride) {
        int kc = i / 3840, r = i - kc * 3840;
        int nn = r / 40, kk = r - nn * 40;
        Wc[O_W2C + i] = (kk < 32) ? f2b(W2[(kc * 32 + kk) * 96 + nn]) : f2b(0.0f);
    }
    if (g < 2) sums[g] = 0.f;
}

// Fragment layouts (HW-verified): A: m=lane&15, k=quad*8+j; B from B^T same;
// C/D: col=lane&15, row=quad*4+reg.
__global__ __launch_bounds__(256) void attn_ffn_kernel(
    const float* __restrict__ x, const __hip_bfloat16* __restrict__ Wc,
    __hip_bfloat16* __restrict__ M)
{
    const int n = blockIdx.x, tid = threadIdx.x;
    const int w = tid >> 6, lane = tid & 63, quad = lane >> 4, ln = lane & 15;

    // LDS layout (50,432 B -> 3 blocks/CU)
    __shared__ __align__(16) char smem[50432];
    __hip_bfloat16* xs  = (__hip_bfloat16*)(smem);          // [64][104] x / att
    __hip_bfloat16* wb  = (__hip_bfloat16*)(smem + 13312);  // 9984 B FFN1 stage
    __hip_bfloat16* PB  = (__hip_bfloat16*)(smem + 13312);  // [64][72] (phase B)
    __hip_bfloat16* kS  = (__hip_bfloat16*)(smem + 23296);  // [64][104] Qscr / K
    __hip_bfloat16* vT  = (__hip_bfloat16*)(smem + 36608);  // [96][72] V^T
    __hip_bfloat16* hid = (__hip_bfloat16*)(smem + 23296);  // [64][200] (phase C)

    const f32x4 z4 = {0.f, 0.f, 0.f, 0.f};
    const int rowb = 16 * w + quad * 4;

    // preload first A-stage weight fragments (Wq rows 0..47)
    bf16x8 wf[9], wfn[9];
    #pragma unroll
    for (int i = 0; i < 9; ++i)
        wf[i] = *(const bf16x8*)(Wc + O_WQT + ((i % 3) * 16 + ln) * 104 + (i / 3) * 32 + quad * 8);

    // stage x: lane-per-row (f=lane), b128 LDS writes (conflict-light)
    {
        const float* xb = x + (size_t)n * 6144;
        const int sb = w * 24;
        for (int c = 0; c < 3; ++c) {
            float v[8];
            #pragma unroll
            for (int j = 0; j < 8; ++j) v[j] = xb[(sb + c * 8 + j) * 64 + lane];
            union { __hip_bfloat16 h[8]; bf16x8 v8; } pk;
            #pragma unroll
            for (int j = 0; j < 8; ++j) pk.h[j] = f2b(v[j]);
            *(bf16x8*)(xs + lane * 104 + sb + c * 8) = pk.v8;
        }
    }
    __syncthreads();                                        // barrier 1

    bf16x8 aqr[3];                                          // Q A-frags (regs)

    // ---------- phase A: Q/K/V via register weight frags (no barriers) ----------
    for (int st = 0; st < 6; ++st) {
        const int t = st >> 1, half = st & 1;
        if (st < 5) {
            const __hip_bfloat16* nb = Wc + ((st + 1) >> 1) * 10080 + ((st + 1) & 1) * 4992;
            #pragma unroll
            for (int i = 0; i < 9; ++i)
                wfn[i] = *(const bf16x8*)(nb + ((i % 3) * 16 + ln) * 104 + (i / 3) * 32 + quad * 8);
        }
        f32x4 acc[3] = {z4, z4, z4};
        #pragma unroll
        for (int ks = 0; ks < 3; ++ks) {
            bf16x8 a = *(const bf16x8*)(xs + (16 * w + ln) * 104 + ks * 32 + quad * 8);
            #pragma unroll
            for (int ct = 0; ct < 3; ++ct)
                acc[ct] = __builtin_amdgcn_mfma_f32_16x16x32_bf16(a, wf[ks * 3 + ct], acc[ct], 0, 0, 0);
        }
        const int j0 = half * 48;
        const __hip_bfloat16* bt = Wc + 9984 + t * 10080;
        #pragma unroll
        for (int ct = 0; ct < 3; ++ct) {
            int col = j0 + ct * 16 + ln;
            float bb = b2f(bt[col]);
            if (t < 2) {                                    // Q scratch / K (wave-local rows)
                #pragma unroll
                for (int r = 0; r < 4; ++r)
                    kS[(rowb + r) * 104 + col] = f2b(acc[ct][r] + bb);
            } else {                                        // V^T: 4 consecutive -> uint2
                union { __hip_bfloat16 h4[4]; uint2 u; } pk;
                #pragma unroll
                for (int r = 0; r < 4; ++r) pk.h4[r] = f2b(acc[ct][r] + bb);
                *(uint2*)(vT + col * 72 + rowb) = pk.u;
            }
        }
        if (t == 0 && half == 1) {                          // own-wave rows -> no barrier
            #pragma unroll
            for (int h = 0; h < 3; ++h)
                aqr[h] = *(const bf16x8*)(kS + (16 * w + ln) * 104 + h * 32 + quad * 8);
        }
        #pragma unroll
        for (int i = 0; i < 9; ++i) wf[i] = wfn[i];
    }

    bf16x8 erf[4];                                          // Er B-frags (global, cached)
    #pragma unroll
    for (int tn = 0; tn < 4; ++tn)
        erf[tn] = *(const bf16x8*)(Wc + O_ER + (16 * tn + ln) * 32 + quad * 8);
    __syncthreads();                                        // barrier 2: K/V visible

    // FFN1 stage-0 prefetch (consumed in phase C; plenty of window here)
    bf16x8 pf0, pf1, pf2;
    {
        const bf16x8* src = (const bf16x8*)(Wc + O_W1T);
        pf0 = src[tid]; pf1 = src[tid + 256];
        if (tid + 512 < 624) pf2 = src[tid + 512];
    }

    // ---------- phase B: MFMA attention (barrier-free) ----------
    for (int h = 0; h < 3; ++h) {
        const int c0 = h * 32;
        bf16x8 aq = aqr[h];
        #pragma unroll
        for (int tn = 0; tn < 4; ++tn) {                    // Qer -> PB (own rows)
            f32x4 q4 = __builtin_amdgcn_mfma_f32_16x16x32_bf16(aq, erf[tn], z4, 0, 0, 0);
            #pragma unroll
            for (int r = 0; r < 4; ++r)
                PB[(rowb + r) * 72 + 16 * tn + ln] = f2b(q4[r]);
        }
        float sco[4][4];
        #pragma unroll
        for (int tn = 0; tn < 4; ++tn) {
            bf16x8 kf = *(const bf16x8*)(kS + (16 * tn + ln) * 104 + c0 + quad * 8);
            f32x4 s1 = __builtin_amdgcn_mfma_f32_16x16x32_bf16(aq, kf, z4, 0, 0, 0);
            #pragma unroll
            for (int r = 0; r < 4; ++r) sco[tn][r] = s1[r];
        }
        #pragma unroll
        for (int tn = 0; tn < 4; ++tn)
            #pragma unroll
            for (int r = 0; r < 4; ++r) {
                int row = rowb + r, col = 16 * tn + ln;
                if (col <= row)
                    sco[tn][r] = (sco[tn][r] + b2f(PB[row * 72 + col + 63 - row]))
                                 * 0.17677669529663687f;
                else
                    sco[tn][r] = -3.0e38f;
            }
        float mx[4], sm[4];
        #pragma unroll
        for (int r = 0; r < 4; ++r) {
            float m0 = fmaxf(fmaxf(sco[0][r], sco[1][r]), fmaxf(sco[2][r], sco[3][r]));
            #pragma unroll
            for (int d = 1; d < 16; d <<= 1) m0 = fmaxf(m0, __shfl_xor(m0, d, 64));
            mx[r] = m0;
        }
        #pragma unroll
        for (int tn = 0; tn < 4; ++tn)
            #pragma unroll
            for (int r = 0; r < 4; ++r) sco[tn][r] = __expf(sco[tn][r] - mx[r]);
        #pragma unroll
        for (int r = 0; r < 4; ++r) {
            float s0 = sco[0][r] + sco[1][r] + sco[2][r] + sco[3][r];
            #pragma unroll
            for (int d = 1; d < 16; d <<= 1) s0 += __shfl_xor(s0, d, 64);
            sm[r] = 1.0f / s0;
        }
        #pragma unroll
        for (int tn = 0; tn < 4; ++tn)
            #pragma unroll
            for (int r = 0; r < 4; ++r)
                PB[(rowb + r) * 72 + 16 * tn + ln] = f2b(sco[tn][r] * sm[r]);
        f32x4 oacc[2] = {z4, z4};
        #pragma unroll
        for (int ks2 = 0; ks2 < 2; ++ks2) {
            bf16x8 pa = *(const bf16x8*)(PB + (16 * w + ln) * 72 + ks2 * 32 + quad * 8);
            #pragma unroll
            for (int t2 = 0; t2 < 2; ++t2) {
                bf16x8 vb = *(const bf16x8*)(vT + (c0 + 16 * t2 + ln) * 72 + ks2 * 32 + quad * 8);
                oacc[t2] = __builtin_amdgcn_mfma_f32_16x16x32_bf16(pa, vb, oacc[t2], 0, 0, 0);
            }
        }
        #pragma unroll
        for (int t2 = 0; t2 < 2; ++t2)
            #pragma unroll
            for (int r = 0; r < 4; ++r)
                xs[(rowb + r) * 104 + c0 + 16 * t2 + ln] = f2b(oacc[t2][r]);
    }
    __syncthreads();                                        // barrier 3: hid overlays kS/vT

    // ---------- phase C: FFN (FFN1 LDS-pipelined; FFN2 register frags) ----------
    f32x4 acc2[6] = {z4, z4, z4, z4, z4, z4};
    bf16x8 w2f[6], w2fn[6];
    for (int jh = 0; jh < 2; ++jh) {
        for (int cc = 0; cc < 4; ++cc) {                    // FFN1 stages (624 vecs)
            const int j0g = jh * 192 + cc * 48;
            __syncthreads();                                // wb/PB consumers done
            {
                bf16x8* dst = (bf16x8*)wb;
                dst[tid] = pf0;
                dst[tid + 256] = pf1;
                if (tid + 512 < 624) dst[tid + 512] = pf2;
                if (cc < 3) {                               // next W1 chunk
                    const bf16x8* src = (const bf16x8*)(Wc + O_W1T + jh * 19968 + (cc + 1) * 4992);
                    pf0 = src[tid]; pf1 = src[tid + 256];
                    if (tid + 512 < 624) pf2 = src[tid + 512];
                } else {                                    // FFN2 kc=0 frags
                    const __hip_bfloat16* nb = Wc + O_W2C + (jh * 6) * 3840;
                    #pragma unroll
                    for (int ct = 0; ct < 6; ++ct)
                        w2f[ct] = *(const bf16x8*)(nb + (ct * 16 + ln) * 40 + quad * 8);
                }
            }
            __syncthreads();
            f32x4 a1[3] = {z4, z4, z4};
            #pragma unroll
            for (int ks = 0; ks < 3; ++ks) {
                bf16x8 a = *(const bf16x8*)(xs + (16 * w + ln) * 104 + ks * 32 + quad * 8);
                #pragma unroll
                for (int ct = 0; ct < 3; ++ct) {
                    bf16x8 b = *(const bf16x8*)(wb + (ct * 16 + ln) * 104 + ks * 32 + quad * 8);
                    a1[ct] = __builtin_amdgcn_mfma_f32_16x16x32_bf16(a, b, a1[ct], 0, 0, 0);
                }
            }
            #pragma unroll
            for (int ct = 0; ct < 3; ++ct) {
                int colg = j0g + ct * 16 + ln;
                int coll = cc * 48 + ct * 16 + ln;
                float bb = b2f(Wc[O_B1 + colg]);
                #pragma unroll
                for (int r = 0; r < 4; ++r)
                    hid[(rowb + r) * 200 + coll] = f2b(fmaxf(a1[ct][r] + bb, 0.f));
            }
        }
        for (int kc = 0; kc < 6; ++kc) {                    // FFN2: reg frags, no barriers
            if (kc < 5) {
                const __hip_bfloat16* nb = Wc + O_W2C + (jh * 6 + kc + 1) * 3840;
                #pragma unroll
                for (int ct = 0; ct < 6; ++ct)
                    w2fn[ct] = *(const bf16x8*)(nb + (ct * 16 + ln) * 40 + quad * 8);
            } else if (jh == 0) {                           // FFN1 jh1 cc0 prefetch
                const bf16x8* src = (const bf16x8*)(Wc + O_W1T + 19968);
                pf0 = src[tid]; pf1 = src[tid + 256];
                if (tid + 512 < 624) pf2 = src[tid + 512];
            }
            bf16x8 a = *(const bf16x8*)(hid + (16 * w + ln) * 200 + kc * 32 + quad * 8);
            #pragma unroll
            for (int ct = 0; ct < 6; ++ct)
                acc2[ct] = __builtin_amdgcn_mfma_f32_16x16x32_bf16(a, w2f[ct], acc2[ct], 0, 0, 0);
            if (kc < 5) {
                #pragma unroll
                for (int ct = 0; ct < 6; ++ct) w2f[ct] = w2fn[ct];
            }
        }
    }

    // epilogue: M[n][d*64 + l] = acc2 + b2[d], packed 8B stores
    __hip_bfloat16* Mg = M + (size_t)n * 6144;
    #pragma unroll
    for (int ct = 0; ct < 6; ++ct) {
        int d = ct * 16 + ln;
        float bb = b2f(Wc[O_B2 + d]);
        union { __hip_bfloat16 h4[4]; uint2 u; } pk;
        #pragma unroll
        for (int r = 0; r < 4; ++r) pk.h4[r] = f2b(acc2[ct][r] + bb);
        *(uint2*)((char*)Mg + (size_t)(d * 64 + rowb) * 2) = pk.u;
    }
}

// Y = A @ We + be, with mean/var partial reduction fused into the epilogue.
// A+B double-buffered LDS, register prefetch, 1 barrier/iter.
__global__ __launch_bounds__(256) void gemm_kernel(
    const __hip_bfloat16* __restrict__ A,    // 4096 x 6144 (M workspace)
    const __hip_bfloat16* __restrict__ Wc,
    const float* __restrict__ be,            // fp32 bias (512)
    float* __restrict__ Y,                   // 4096 x 512
    float* __restrict__ sums)                // 2 floats (pre-zeroed)
{
    __shared__ __align__(16) __hip_bfloat16 As[2][64 * 72];
    __shared__ __align__(16) __hip_bfloat16 Bs[2][64 * 72];
    const int row0 = blockIdx.x * 64, nt = blockIdx.y, col0 = nt * 64;
    const int tid = threadIdx.x;
    const int w = tid >> 6, lane = tid & 63, quad = lane >> 4, ln = lane & 15;
    const int r0 = tid >> 3, c0_ = (tid & 7) * 8;
    const int r1 = r0 + 32,  c1_ = c0_;
    const size_t abase0 = (size_t)(row0 + r0) * 6144 + c0_;
    const size_t abase1 = (size_t)(row0 + r1) * 6144 + c1_;
    const __hip_bfloat16* Bsrc = Wc + O_WET + (size_t)nt * 96 * 4096;
    const size_t bbase0 = (size_t)r0 * 64 + c0_;
    const size_t bbase1 = (size_t)r1 * 64 + c1_;

    const f32x4 z4 = {0.f, 0.f, 0.f, 0.f};
    f32x4 acc[4] = {z4, z4, z4, z4};

    bf16x8 pa0 = *(const bf16x8*)(A + abase0);
    bf16x8 pa1 = *(const bf16x8*)(A + abase1);
    bf16x8 pb0 = *(const bf16x8*)(Bsrc + bbase0);
    bf16x8 pb1 = *(const bf16x8*)(Bsrc + bbase1);
    *(bf16x8*)(&As[0][r0 * 72 + c0_]) = pa0;
    *(bf16x8*)(&As[0][r1 * 72 + c1_]) = pa1;
    *(bf16x8*)(&Bs[0][r0 * 72 + c0_]) = pb0;
    *(bf16x8*)(&Bs[0][r1 * 72 + c1_]) = pb1;
    __syncthreads();

    for (int kt = 0; kt < 96; ++kt) {
        const int cur = kt & 1;
        if (kt < 95) {
            pa0 = *(const bf16x8*)(A + abase0 + (kt + 1) * 64);
            pa1 = *(const bf16x8*)(A + abase1 + (kt + 1) * 64);
            pb0 = *(const bf16x8*)(Bsrc + (size_t)(kt + 1) * 4096 + bbase0);
            pb1 = *(const bf16x8*)(Bsrc + (size_t)(kt + 1) * 4096 + bbase1);
        }
        #pragma unroll
        for (int ks = 0; ks < 2; ++ks) {
            bf16x8 a = *(const bf16x8*)(&As[cur][(16 * w + ln) * 72 + ks * 32 + quad * 8]);
            #pragma unroll
            for (int tn = 0; tn < 4; ++tn) {
                bf16x8 b = *(const bf16x8*)(&Bs[cur][(16 * tn + ln) * 72 + ks * 32 + quad * 8]);
                acc[tn] = __builtin_amdgcn_mfma_f32_16x16x32_bf16(a, b, acc[tn], 0, 0, 0);
            }
        }
        if (kt < 95) {
            *(bf16x8*)(&As[cur ^ 1][r0 * 72 + c0_]) = pa0;
            *(bf16x8*)(&As[cur ^ 1][r1 * 72 + c1_]) = pa1;
            *(bf16x8*)(&Bs[cur ^ 1][r0 * 72 + c0_]) = pb0;
            *(bf16x8*)(&Bs[cur ^ 1][r1 * 72 + c1_]) = pb1;
        }
        __syncthreads();
    }
    float s = 0.f, s2 = 0.f;
    #pragma unroll
    for (int tn = 0; tn < 4; ++tn) {
        int col = col0 + 16 * tn + ln;
        float bb = be[col];
        #pragma unroll
        for (int r = 0; r < 4; ++r) {
            float v = acc[tn][r] + bb;
            Y[(size_t)(row0 + 16 * w + quad * 4 + r) * 512 + col] = v;
            s += v; s2 += v * v;
        }
    }
    #pragma unroll
    for (int off = 1; off < 64; off <<= 1) {
        s  += __shfl_xor(s, off, 64);
        s2 += __shfl_xor(s2, off, 64);
    }
    __shared__ float r1s[4], r2s[4];
    if (lane == 0) { r1s[w] = s; r2s[w] = s2; }
    __syncthreads();
    if (tid == 0) {
        atomicAdd(&sums[0], r1s[0] + r1s[1] + r1s[2] + r1s[3]);
        atomicAdd(&sums[1], r2s[0] + r2s[1] + r2s[2] + r2s[3]);
    }
}

// parallel per-row scan: bid[t] = (incl prefix of o)[t] - o[0]
__global__ __launch_bounds__(256) void segid_kernel(const int* __restrict__ o_enc,
                                                    int* __restrict__ bids) {
    __shared__ int ts[256];
    const int b = blockIdx.x, tid = threadIdx.x;
    const int* o = o_enc + b * 1024;
    int v0 = o[4 * tid], v1 = o[4 * tid + 1], v2 = o[4 * tid + 2], v3 = o[4 * tid + 3];
    int p0 = v0, p1 = p0 + v1, p2 = p1 + v2, p3 = p2 + v3;
    ts[tid] = p3;
    __syncthreads();
    for (int off = 1; off < 256; off <<= 1) {
        int mine = ts[tid];
        int add = (tid >= off) ? ts[tid - off] : 0;
        __syncthreads();
        ts[tid] = mine + add;
        __syncthreads();
    }
    const int excl = (tid > 0) ? ts[tid - 1] : 0;
    const int off0 = o[0];
    int* bid = bids + b * 1024;
    bid[4 * tid]     = excl + p0 - off0;
    bid[4 * tid + 1] = excl + p1 - off0;
    bid[4 * tid + 2] = excl + p2 - off0;
    bid[4 * tid + 3] = excl + p3 - off0;
}

__global__ __launch_bounds__(256) void final_kernel(
    const float* __restrict__ Y, const int* __restrict__ bids,
    const float* __restrict__ sums, const float* __restrict__ r_enc,
    float* __restrict__ out)
{
    const int bt = blockIdx.x;
    const int b = bt >> 10, t = bt & 1023;
    const float mu = sums[0] * (1.0f / 2097152.0f);
    const float var = sums[1] * (1.0f / 2097152.0f) - mu * mu;
    const float rstd = rsqrtf(var + 1e-8f);
    const int* bid = bids + b * 1024;
    const int my = bid[t];
    const bool is_start = (t == 0) || (bid[t - 1] != my);
    int t2 = t + 1;
    float invc = 0.f;
    if (is_start) {
        while (t2 < 1024 && bid[t2] == my) ++t2;
        invc = 1.0f / (float)(t2 - t);
    }
    for (int e = threadIdx.x; e < 512; e += 256) {
        const size_t base = (size_t)bt * 512 + e;
        float res = (Y[base] - mu) * rstd + r_enc[base];
        if (is_start) {
            float s = 0.f;
            for (int tt = t; tt < t2; ++tt)
                s += (Y[((size_t)(b * 1024 + tt)) * 512 + e] - mu) * rstd;
            res += s * invc;
        }
        out[base] = res;
    }
}

extern "C" void kernel_launch(void* const* d_in, const int* in_sizes, int n_in,
                              void* d_out, int out_size, void* d_ws, size_t ws_size,
                              hipStream_t stream) {
    PtrTab tab;
    for (int i = 0; i < 16; ++i) tab.p[i] = d_in[i];

    char* ws = (char*)d_ws;
    __hip_bfloat16* M  = (__hip_bfloat16*)ws;
    float* Y           = (float*)(ws + 50331648);
    float* sums        = (float*)(ws + 58720256);
    int*   bids        = (int*)(ws + 58720320);
    __hip_bfloat16* Wc = (__hip_bfloat16*)(ws + 58736768);

    prep_kernel<<<768, 256, 0, stream>>>(tab, Wc, sums);
    attn_ffn_kernel<<<4096, 256, 0, stream>>>((const float*)d_in[0], Wc, M);
    gemm_kernel<<<dim3(64, 8), 256, 0, stream>>>(M, Wc, (const float*)d_in[15], Y, sums);
    segid_kernel<<<4, 256, 0, stream>>>((const int*)d_in[1], bids);
    final_kernel<<<4096, 256, 0, stream>>>(Y, bids, sums, (const float*)d_in[2], (float*)d_out);
}